// Round 6
// baseline (380.502 us; speedup 1.0000x reference)
//
#include <hip/hip_runtime.h>
#include <hip/hip_bf16.h>

typedef unsigned int uint;
typedef unsigned short ushort;

#define N_NODES 50000
#define N_EDGES 800000
#define FDIM 128
#define HID 64
#define NPERM 128
#define HLLM 64

#define BSHIFT 8
#define BNODES 256                 // nodes per bucket
#define NBUCK 196                  // ceil(50000/256)
#define SCAT_BLOCKS 256
#define EDGES_PER_BLK 3125         // 800000/256 exactly
#define HIST_BLOCKS 64
#define EDGES_PER_HIST 12500       // 800000/64 exactly
#define MH_BLOCKS 12500            // 50000*64/256 (pack)
#define HLL_BLOCKS 3125            // 50000*16/256 (pack)
#define SLICE_CAP 6400
#define GATHER_BLOCKS 12500        // 4 nodes (waves) per 256-block

// ---------------- prep: pack hashes (chunked layouts) + dst histogram ----------------

__global__ void k_prep(const int* __restrict__ mh, uint* __restrict__ mhp,
                       const int* __restrict__ hll, uint* __restrict__ hp,
                       const int* __restrict__ dst, int* __restrict__ hist2d) {
    int b = blockIdx.x;
    if (b < MH_BLOCKS) {
        // minhash int32 -> top16(float32) u16 (monotone, err <= |v|/128),
        // chunked layout: mhp[(u>>4)*N + node][u&15], uint u covers perms 2u,2u+1
        int i = b * 256 + threadIdx.x;
        int2 v = ((const int2*)mh)[i];
        uint u0 = __float_as_uint((float)v.x) >> 16;
        uint u1 = __float_as_uint((float)v.y) >> 16;
        int node = i >> 6, u = i & 63;
        mhp[(size_t)((u >> 4) * N_NODES + node) * 16 + (u & 15)] = u0 | (u1 << 16);
    } else if (b < MH_BLOCKS + HLL_BLOCKS) {
        // hll int32 (<20; max-only keeps <256) -> u8 packed, [node][16 uints]
        int i = (b - MH_BLOCKS) * 256 + threadIdx.x;
        int4 v = ((const int4*)hll)[i];
        hp[i] = (uint)v.x | ((uint)v.y << 8) | ((uint)v.z << 16) | ((uint)v.w << 24);
    } else {
        int hb = b - MH_BLOCKS - HLL_BLOCKS;
        __shared__ int h[NBUCK];
        for (int i = threadIdx.x; i < NBUCK; i += 256) h[i] = 0;
        __syncthreads();
        int e0 = hb * EDGES_PER_HIST;
        for (int i = threadIdx.x; i < EDGES_PER_HIST; i += 256)
            atomicAdd(&h[dst[e0 + i] >> BSHIFT], 1);
        __syncthreads();
        for (int i = threadIdx.x; i < NBUCK; i += 256)
            hist2d[hb * NBUCK + i] = h[i];
    }
}

// reduce per-block hists -> bktcnt, exclusive scan -> gbase/gcur
__global__ void k_bktscan(const int* __restrict__ hist2d, int* __restrict__ bktcnt,
                          int* __restrict__ gbase, int* __restrict__ gcur,
                          int* __restrict__ offsets) {
    __shared__ int s[256];
    int t = threadIdx.x;
    int v = 0;
    if (t < NBUCK)
        for (int k = 0; k < HIST_BLOCKS; ++k) v += hist2d[k * NBUCK + t];
    s[t] = v;
    __syncthreads();
    for (int off = 1; off < 256; off <<= 1) {
        int u = (t >= off) ? s[t - off] : 0;
        __syncthreads();
        s[t] += u;
        __syncthreads();
    }
    if (t < NBUCK) {
        int ex = s[t] - v;
        bktcnt[t] = v; gbase[t] = ex; gcur[t] = ex;
    }
    if (t == 0) offsets[N_NODES] = N_EDGES + N_NODES;
}

// ---------------- pass A: block-local multisplit scatter ----------------

__global__ void __launch_bounds__(256) k_scatter(const int* __restrict__ src,
                          const int* __restrict__ dst,
                          int* __restrict__ gcur, uint* __restrict__ ebuf) {
    __shared__ uint ecache[EDGES_PER_BLK];
    __shared__ int cnt[NBUCK];
    __shared__ int cur[NBUCK];
    int t = threadIdx.x;
    for (int i = t; i < NBUCK; i += 256) cnt[i] = 0;
    __syncthreads();
    int e0 = blockIdx.x * EDGES_PER_BLK;
    for (int i = t; i < EDGES_PER_BLK; i += 256) {
        int d = dst[e0 + i];
        int s = src[e0 + i];
        ecache[i] = ((uint)s << 16) | (uint)d;   // both < 65536
        atomicAdd(&cnt[d >> BSHIFT], 1);
    }
    __syncthreads();
    for (int b = t; b < NBUCK; b += 256)
        cur[b] = atomicAdd(&gcur[b], cnt[b]);
    __syncthreads();
    for (int i = t; i < EDGES_PER_BLK; i += 256) {
        uint en = ecache[i];
        uint d = en & 0xFFFFu;
        int p = atomicAdd(&cur[d >> BSHIFT], 1);
        ebuf[p] = ((en >> 16) << BSHIFT) | (d & (BNODES - 1));
    }
}

// ---------------- pass B: build CSR slice (u16) in LDS; emit offsets/dis ----------------

__global__ void __launch_bounds__(256) k_csr(const uint* __restrict__ ebuf,
                      const int* __restrict__ gbase, const int* __restrict__ bktcnt,
                      int* __restrict__ offsets, float* __restrict__ dis,
                      ushort* __restrict__ csr) {
    __shared__ int lcur[BNODES];
    __shared__ int ssum[256];
    __shared__ uint slice[SLICE_CAP];
    int b = blockIdx.x;
    int lo = b << BSHIFT;
    int nbkt = min(BNODES, N_NODES - lo);
    int ebase = gbase[b];
    int ecnt = bktcnt[b];
    int t = threadIdx.x;
    lcur[t] = 0;
    __syncthreads();
    for (int i = t; i < ecnt; i += 256)
        atomicAdd(&lcur[ebuf[ebase + i] & (BNODES - 1)], 1);
    __syncthreads();
    int a0 = lcur[t];
    ssum[t] = a0;
    __syncthreads();
    for (int off = 1; off < 256; off <<= 1) {
        int u = (t >= off) ? ssum[t - off] : 0;
        __syncthreads();
        ssum[t] += u;
        __syncthreads();
    }
    int pre = ssum[t] - a0;
    if (t < nbkt) {
        int st = pre + t;
        slice[st] = (uint)(lo + t);       // self-loop first
        lcur[t] = st + 1;
        offsets[lo + t] = ebase + lo + st;
        dis[lo + t] = rsqrtf((float)(a0 + 1));
    }
    __syncthreads();
    for (int i = t; i < ecnt; i += 256) {
        uint en = ebuf[ebase + i];
        int p = atomicAdd(&lcur[en & (BNODES - 1)], 1);
        slice[p] = en >> BSHIFT;
    }
    __syncthreads();
    int slen = ecnt + nbkt;
    int gb = ebase + lo;
    for (int i = t; i < slen; i += 256) csr[gb + i] = (ushort)slice[i];
}

// ---------------- dense GEMMs ----------------

__global__ void k_encoder(const float* __restrict__ x, const float* __restrict__ W,
                          const float* __restrict__ b, float* __restrict__ h) {
    __shared__ float Ws[FDIM * HID];
    for (int idx = threadIdx.x; idx < FDIM * HID; idx += 256) Ws[idx] = W[idx];
    __syncthreads();
    int row = blockIdx.x * 64 + (threadIdx.x >> 2);
    int c0 = (threadIdx.x & 3) * 16;
    if (row >= N_NODES) return;
    float acc[16];
#pragma unroll
    for (int j = 0; j < 16; ++j) acc[j] = b[c0 + j];
    const float4* xr = (const float4*)(x + (size_t)row * FDIM);
    for (int k4 = 0; k4 < FDIM / 4; ++k4) {
        float4 xv = xr[k4];
        const float* wr = Ws + (k4 * 4) * HID + c0;
#pragma unroll
        for (int j = 0; j < 16; ++j) acc[j] = fmaf(xv.x, wr[j], acc[j]);
#pragma unroll
        for (int j = 0; j < 16; ++j) acc[j] = fmaf(xv.y, wr[HID + j], acc[j]);
#pragma unroll
        for (int j = 0; j < 16; ++j) acc[j] = fmaf(xv.z, wr[2 * HID + j], acc[j]);
#pragma unroll
        for (int j = 0; j < 16; ++j) acc[j] = fmaf(xv.w, wr[3 * HID + j], acc[j]);
    }
    float* hr = h + (size_t)row * HID + c0;
#pragma unroll
    for (int j = 0; j < 16; ++j) hr[j] = acc[j];
}

// hWs = bf16( dis ⊙ (h @ W_k) ), chunked layout [2][N][32]
__global__ void k_convmm(const float* __restrict__ h, const float* __restrict__ W,
                         const float* __restrict__ dis, __hip_bfloat16* __restrict__ hWs) {
    __shared__ float Ws[HID * HID];
    for (int idx = threadIdx.x; idx < HID * HID; idx += 256) Ws[idx] = W[idx];
    __syncthreads();
    int row = blockIdx.x * 64 + (threadIdx.x >> 2);
    int c0 = (threadIdx.x & 3) * 16;
    if (row >= N_NODES) return;
    float acc[16] = {0.f, 0.f, 0.f, 0.f, 0.f, 0.f, 0.f, 0.f,
                     0.f, 0.f, 0.f, 0.f, 0.f, 0.f, 0.f, 0.f};
    const float4* hr = (const float4*)(h + (size_t)row * HID);
    for (int k4 = 0; k4 < HID / 4; ++k4) {
        float4 hv = hr[k4];
        const float* wr = Ws + (k4 * 4) * HID + c0;
#pragma unroll
        for (int j = 0; j < 16; ++j) acc[j] = fmaf(hv.x, wr[j], acc[j]);
#pragma unroll
        for (int j = 0; j < 16; ++j) acc[j] = fmaf(hv.y, wr[HID + j], acc[j]);
#pragma unroll
        for (int j = 0; j < 16; ++j) acc[j] = fmaf(hv.z, wr[2 * HID + j], acc[j]);
#pragma unroll
        for (int j = 0; j < 16; ++j) acc[j] = fmaf(hv.w, wr[3 * HID + j], acc[j]);
    }
    float d = dis[row];
    __hip_bfloat16* o = hWs + (size_t)(c0 >> 5) * (N_NODES * 32)
                            + (size_t)row * 32 + (c0 & 31);
#pragma unroll
    for (int j = 0; j < 16; ++j) o[j] = __float2bfloat16(d * acc[j]);
}

// ---------------- L2-resident chunked gathers ----------------
// One wave per node; lanes = 4 neighbor-slots (g) x 16 dwords (q).
// OOB neighbor slots clamp to the self-loop entry (idempotent for min/max).

__global__ void __launch_bounds__(256) k_mh2(const int* __restrict__ offsets,
                    const ushort* __restrict__ csr, const uint* __restrict__ sl,
                    uint* __restrict__ out_p, float* __restrict__ out_f, int chunk) {
    int tid = threadIdx.x;
    int node = blockIdx.x * 4 + (tid >> 6);
    int g = (tid >> 4) & 3, q = tid & 15;
    int s = offsets[node], e = offsets[node + 1];
    uint mn0 = 0xFFFFu, mn1 = 0xFFFFu, mn2 = 0xFFFFu, mn3 = 0xFFFFu;
    for (int p = s; p < e; p += 8) {
        int pa = p + g;     pa = pa < e ? pa : s;
        int pb = p + 4 + g; pb = pb < e ? pb : s;
        uint ja = csr[pa], jb = csr[pb];
        uint a = sl[(size_t)ja * 16 + q];
        uint b = sl[(size_t)jb * 16 + q];
        mn0 = min(mn0, a & 0xFFFFu); mn1 = min(mn1, a >> 16);
        mn2 = min(mn2, b & 0xFFFFu); mn3 = min(mn3, b >> 16);
    }
    mn0 = min(mn0, mn2); mn1 = min(mn1, mn3);
    mn0 = min(mn0, (uint)__shfl_xor((int)mn0, 16));
    mn0 = min(mn0, (uint)__shfl_xor((int)mn0, 32));
    mn1 = min(mn1, (uint)__shfl_xor((int)mn1, 16));
    mn1 = min(mn1, (uint)__shfl_xor((int)mn1, 32));
    if (g == 0) {
        if (out_p) {
            out_p[(size_t)node * 16 + q] = mn0 | (mn1 << 16);
        } else {
            float2 w;
            w.x = __uint_as_float(mn0 << 16);
            w.y = __uint_as_float(mn1 << 16);
            *(float2*)(out_f + (size_t)node * NPERM + chunk * 32 + 2 * q) = w;
        }
    }
}

__global__ void __launch_bounds__(256) k_hll2(const int* __restrict__ offsets,
                    const ushort* __restrict__ csr, const uint* __restrict__ sl,
                    uint* __restrict__ hout_p, float* __restrict__ hout_f,
                    float* __restrict__ cards, int kcol) {
    int tid = threadIdx.x;
    int node = blockIdx.x * 4 + (tid >> 6);
    int g = (tid >> 4) & 3, q = tid & 15;
    int s = offsets[node], e = offsets[node + 1];
    uint m0 = 0, m1 = 0, m2 = 0, m3 = 0;
    for (int p = s; p < e; p += 8) {
        int pa = p + g;     pa = pa < e ? pa : s;
        int pb = p + 4 + g; pb = pb < e ? pb : s;
        uint a = sl[(size_t)csr[pa] * 16 + q];
        uint b = sl[(size_t)csr[pb] * 16 + q];
        m0 = max(m0, a & 0xFFu); m1 = max(m1, (a >> 8) & 0xFFu);
        m2 = max(m2, (a >> 16) & 0xFFu); m3 = max(m3, a >> 24);
        m0 = max(m0, b & 0xFFu); m1 = max(m1, (b >> 8) & 0xFFu);
        m2 = max(m2, (b >> 16) & 0xFFu); m3 = max(m3, b >> 24);
    }
    m0 = max(m0, (uint)__shfl_xor((int)m0, 16)); m0 = max(m0, (uint)__shfl_xor((int)m0, 32));
    m1 = max(m1, (uint)__shfl_xor((int)m1, 16)); m1 = max(m1, (uint)__shfl_xor((int)m1, 32));
    m2 = max(m2, (uint)__shfl_xor((int)m2, 16)); m2 = max(m2, (uint)__shfl_xor((int)m2, 32));
    m3 = max(m3, (uint)__shfl_xor((int)m3, 16)); m3 = max(m3, (uint)__shfl_xor((int)m3, 32));
    if (g == 0) {
        if (hout_p) hout_p[(size_t)node * 16 + q] = m0 | (m1 << 8) | (m2 << 16) | (m3 << 24);
        if (hout_f) {
            float4 w = {(float)m0, (float)m1, (float)m2, (float)m3};
            *(float4*)(hout_f + (size_t)node * HLLM + 4 * q) = w;
        }
    }
    float v = exp2f(-(float)m0) + exp2f(-(float)m1) + exp2f(-(float)m2) + exp2f(-(float)m3);
    v += __shfl_xor(v, 1); v += __shfl_xor(v, 2);
    v += __shfl_xor(v, 4); v += __shfl_xor(v, 8);
    if ((tid & 63) == 0) {
        const float alphamm = (float)(0.7213 / (1.0 + 1.079 / 64.0) * 64.0 * 64.0);
        cards[(size_t)node * 2 + kcol] = alphamm / v;
    }
}

__global__ void __launch_bounds__(256) k_agg2(const int* __restrict__ offsets,
                    const ushort* __restrict__ csr, const uint* __restrict__ sl,
                    const float* __restrict__ dis, const float* __restrict__ b,
                    const float* __restrict__ h_in, float* __restrict__ h_out, int chunk) {
    int tid = threadIdx.x;
    int node = blockIdx.x * 4 + (tid >> 6);
    int g = (tid >> 4) & 3, q = tid & 15;
    int s = offsets[node], e = offsets[node + 1];
    float ax = 0.f, ay = 0.f, bx = 0.f, by = 0.f;
    for (int p = s; p < e; p += 8) {
        int pa = p + g, pb = p + 4 + g;
        bool va = pa < e, vb = pb < e;
        uint ja = csr[va ? pa : s], jb = csr[vb ? pb : s];
        uint a  = sl[(size_t)ja * 16 + q];
        uint b2 = sl[(size_t)jb * 16 + q];
        if (va) {
            ax += __uint_as_float(a << 16);
            ay += __uint_as_float(a & 0xFFFF0000u);
        }
        if (vb) {
            bx += __uint_as_float(b2 << 16);
            by += __uint_as_float(b2 & 0xFFFF0000u);
        }
    }
    ax += bx; ay += by;
    ax += __shfl_xor(ax, 16); ax += __shfl_xor(ax, 32);
    ay += __shfl_xor(ay, 16); ay += __shfl_xor(ay, 32);
    if (g == 0) {
        int ch = chunk * 32 + 2 * q;
        size_t idx = (size_t)node * HID + ch;
        float2 hi = *(const float2*)(h_in + idx);
        float d = dis[node];
        float2 o;
        o.x = hi.x + b[ch] + d * ax;
        o.y = hi.y + b[ch + 1] + d * ay;
        *(float2*)(h_out + idx) = o;
    }
}

// ---------------- driver ----------------

static inline char* align256(char* p) {
    return (char*)(((uintptr_t)p + 255) & ~(uintptr_t)255);
}

extern "C" void kernel_launch(void* const* d_in, const int* in_sizes, int n_in,
                              void* d_out, int out_size, void* d_ws, size_t ws_size,
                              hipStream_t stream) {
    const float* x       = (const float*)d_in[0];
    const int*   ei      = (const int*)d_in[1];
    const int*   mh0     = (const int*)d_in[2];
    const int*   hll0    = (const int*)d_in[3];
    const float* W_enc   = (const float*)d_in[4];
    const float* b_enc   = (const float*)d_in[5];
    const float* W_convs = (const float*)d_in[6];
    const float* b_convs = (const float*)d_in[7];

    float* out       = (float*)d_out;
    float* out_h     = out;
    float* out_cards = out + (size_t)N_NODES * HID;
    float* out_mh    = out_cards + (size_t)N_NODES * 2;
    float* out_hll   = out_mh + (size_t)N_NODES * NPERM;

    char* w = (char*)d_ws;
    int*   hist2d  = (int*)w;   w = align256(w + (size_t)HIST_BLOCKS * NBUCK * 4);
    int*   bktcnt  = (int*)w;   w = align256(w + (size_t)NBUCK * 4);
    int*   gbase   = (int*)w;   w = align256(w + (size_t)NBUCK * 4);
    int*   gcur    = (int*)w;   w = align256(w + (size_t)NBUCK * 4);
    int*   offsets = (int*)w;   w = align256(w + (size_t)(N_NODES + 1) * 4);
    float* dis     = (float*)w; w = align256(w + (size_t)N_NODES * 4);
    ushort* csr    = (ushort*)w; w = align256(w + (size_t)(N_EDGES + N_NODES) * 2);
    uint*  mhp0    = (uint*)w;  w = align256(w + (size_t)N_NODES * 64 * 4);
    uint*  mhA     = (uint*)w;  w = align256(w + (size_t)N_NODES * 64 * 4);
    uint*  hp0     = (uint*)w;  w = align256(w + (size_t)N_NODES * 16 * 4);
    uint*  hllA    = (uint*)w;  w = align256(w + (size_t)N_NODES * 16 * 4);
    float* h_cur   = (float*)w; w = align256(w + (size_t)N_NODES * HID * 4);
    __hip_bfloat16* hWs = (__hip_bfloat16*)w;
    uint*  ebuf    = mhA;  // build-phase only; mhA first written after k_csr consumed ebuf

    const int* src = ei;
    const int* dst = ei + N_EDGES;

    k_prep<<<MH_BLOCKS + HLL_BLOCKS + HIST_BLOCKS, 256, 0, stream>>>(mh0, mhp0, hll0, hp0, dst, hist2d);
    k_bktscan<<<1, 256, 0, stream>>>(hist2d, bktcnt, gbase, gcur, offsets);
    k_scatter<<<SCAT_BLOCKS, 256, 0, stream>>>(src, dst, gcur, ebuf);
    k_csr<<<NBUCK, 256, 0, stream>>>(ebuf, gbase, bktcnt, offsets, dis, csr);
    k_encoder<<<(N_NODES + 63) / 64, 256, 0, stream>>>(x, W_enc, b_enc, h_cur);

    // ---- hop 0 ----
    k_hll2<<<GATHER_BLOCKS, 256, 0, stream>>>(offsets, csr, hp0, hllA, nullptr, out_cards, 0);
    for (int c = 0; c < 4; ++c)
        k_mh2<<<GATHER_BLOCKS, 256, 0, stream>>>(offsets, csr,
            mhp0 + (size_t)c * N_NODES * 16, mhA + (size_t)c * N_NODES * 16, nullptr, c);
    k_convmm<<<(N_NODES + 63) / 64, 256, 0, stream>>>(h_cur, W_convs, dis, hWs);
    for (int c = 0; c < 2; ++c)
        k_agg2<<<GATHER_BLOCKS, 256, 0, stream>>>(offsets, csr,
            (const uint*)hWs + (size_t)c * N_NODES * 16, dis, b_convs, h_cur, h_cur, c);

    // ---- hop 1 ----
    k_hll2<<<GATHER_BLOCKS, 256, 0, stream>>>(offsets, csr, hllA, nullptr, out_hll, out_cards, 1);
    for (int c = 0; c < 4; ++c)
        k_mh2<<<GATHER_BLOCKS, 256, 0, stream>>>(offsets, csr,
            mhA + (size_t)c * N_NODES * 16, nullptr, out_mh, c);
    k_convmm<<<(N_NODES + 63) / 64, 256, 0, stream>>>(h_cur, W_convs + HID * HID, dis, hWs);
    for (int c = 0; c < 2; ++c)
        k_agg2<<<GATHER_BLOCKS, 256, 0, stream>>>(offsets, csr,
            (const uint*)hWs + (size_t)c * N_NODES * 16, dis, b_convs + HID, h_cur, out_h, c);
}

// Round 7
// 312.343 us; speedup vs baseline: 1.2182x; 1.2182x over previous
//
#include <hip/hip_runtime.h>
#include <hip/hip_bf16.h>

typedef unsigned int uint;
typedef unsigned short ushort;

#define N_NODES 50000
#define N_EDGES 800000
#define FDIM 128
#define HID 64
#define NPERM 128
#define HLLM 64

#define BSHIFT 8
#define BNODES 256                 // nodes per bucket
#define NBUCK 196                  // ceil(50000/256)
#define SCAT_BLOCKS 256
#define EDGES_PER_BLK 3125         // 800000/256 exactly
#define HIST_BLOCKS 64
#define EDGES_PER_HIST 12500       // 800000/64 exactly
#define MH_BLOCKS 12500            // 50000*64/256 (pack)
#define HLL_BLOCKS 3125            // 50000*16/256 (pack)
#define SLICE_CAP 6400

// ---------------- prep: pack hashes + dst histogram ----------------

__global__ void k_prep(const int* __restrict__ mh, uint* __restrict__ mhp,
                       const int* __restrict__ hll, uint* __restrict__ hp,
                       const int* __restrict__ dst, int* __restrict__ hist2d) {
    int b = blockIdx.x;
    if (b < MH_BLOCKS) {
        // minhash int32 -> top16(float32) u16 (monotone, err <= |v|/128)
        int i = b * 256 + threadIdx.x;
        int2 v = ((const int2*)mh)[i];
        uint u0 = __float_as_uint((float)v.x) >> 16;
        uint u1 = __float_as_uint((float)v.y) >> 16;
        mhp[i] = u0 | (u1 << 16);
    } else if (b < MH_BLOCKS + HLL_BLOCKS) {
        // hll int32 (<20; max-only keeps <256) -> u8 packed
        int i = (b - MH_BLOCKS) * 256 + threadIdx.x;
        int4 v = ((const int4*)hll)[i];
        hp[i] = (uint)v.x | ((uint)v.y << 8) | ((uint)v.z << 16) | ((uint)v.w << 24);
    } else {
        int hb = b - MH_BLOCKS - HLL_BLOCKS;
        __shared__ int h[NBUCK];
        for (int i = threadIdx.x; i < NBUCK; i += 256) h[i] = 0;
        __syncthreads();
        int e0 = hb * EDGES_PER_HIST;
        for (int i = threadIdx.x; i < EDGES_PER_HIST; i += 256)
            atomicAdd(&h[dst[e0 + i] >> BSHIFT], 1);
        __syncthreads();
        for (int i = threadIdx.x; i < NBUCK; i += 256)
            hist2d[hb * NBUCK + i] = h[i];
    }
}

// reduce per-block hists -> bktcnt, exclusive scan -> gbase/gcur
__global__ void k_bktscan(const int* __restrict__ hist2d, int* __restrict__ bktcnt,
                          int* __restrict__ gbase, int* __restrict__ gcur,
                          int* __restrict__ offsets) {
    __shared__ int s[256];
    int t = threadIdx.x;
    int v = 0;
    if (t < NBUCK)
        for (int k = 0; k < HIST_BLOCKS; ++k) v += hist2d[k * NBUCK + t];
    s[t] = v;
    __syncthreads();
    for (int off = 1; off < 256; off <<= 1) {
        int u = (t >= off) ? s[t - off] : 0;
        __syncthreads();
        s[t] += u;
        __syncthreads();
    }
    if (t < NBUCK) {
        int ex = s[t] - v;
        bktcnt[t] = v; gbase[t] = ex; gcur[t] = ex;
    }
    if (t == 0) offsets[N_NODES] = N_EDGES + N_NODES;
}

// ---------------- pass A: block-local multisplit scatter ----------------

__global__ void __launch_bounds__(256) k_scatter(const int* __restrict__ src,
                          const int* __restrict__ dst,
                          int* __restrict__ gcur, uint* __restrict__ ebuf) {
    __shared__ uint ecache[EDGES_PER_BLK];
    __shared__ int cnt[NBUCK];
    __shared__ int cur[NBUCK];
    int t = threadIdx.x;
    for (int i = t; i < NBUCK; i += 256) cnt[i] = 0;
    __syncthreads();
    int e0 = blockIdx.x * EDGES_PER_BLK;
    for (int i = t; i < EDGES_PER_BLK; i += 256) {
        int d = dst[e0 + i];
        int s = src[e0 + i];
        ecache[i] = ((uint)s << 16) | (uint)d;   // both < 65536
        atomicAdd(&cnt[d >> BSHIFT], 1);
    }
    __syncthreads();
    for (int b = t; b < NBUCK; b += 256)
        cur[b] = atomicAdd(&gcur[b], cnt[b]);
    __syncthreads();
    for (int i = t; i < EDGES_PER_BLK; i += 256) {
        uint en = ecache[i];
        uint d = en & 0xFFFFu;
        int p = atomicAdd(&cur[d >> BSHIFT], 1);
        ebuf[p] = ((en >> 16) << BSHIFT) | (d & (BNODES - 1));
    }
}

// ---------------- pass B: build CSR slice (u16) in LDS; emit offsets/dis ----------------

__global__ void __launch_bounds__(256) k_csr(const uint* __restrict__ ebuf,
                      const int* __restrict__ gbase, const int* __restrict__ bktcnt,
                      int* __restrict__ offsets, float* __restrict__ dis,
                      ushort* __restrict__ csr) {
    __shared__ int lcur[BNODES];
    __shared__ int ssum[256];
    __shared__ uint slice[SLICE_CAP];
    int b = blockIdx.x;
    int lo = b << BSHIFT;
    int nbkt = min(BNODES, N_NODES - lo);
    int ebase = gbase[b];
    int ecnt = bktcnt[b];
    int t = threadIdx.x;
    lcur[t] = 0;
    __syncthreads();
    for (int i = t; i < ecnt; i += 256)
        atomicAdd(&lcur[ebuf[ebase + i] & (BNODES - 1)], 1);
    __syncthreads();
    int a0 = lcur[t];
    ssum[t] = a0;
    __syncthreads();
    for (int off = 1; off < 256; off <<= 1) {
        int u = (t >= off) ? ssum[t - off] : 0;
        __syncthreads();
        ssum[t] += u;
        __syncthreads();
    }
    int pre = ssum[t] - a0;
    if (t < nbkt) {
        int st = pre + t;
        slice[st] = (uint)(lo + t);       // self-loop first
        lcur[t] = st + 1;
        offsets[lo + t] = ebase + lo + st;
        dis[lo + t] = rsqrtf((float)(a0 + 1));
    }
    __syncthreads();
    for (int i = t; i < ecnt; i += 256) {
        uint en = ebuf[ebase + i];
        int p = atomicAdd(&lcur[en & (BNODES - 1)], 1);
        slice[p] = en >> BSHIFT;
    }
    __syncthreads();
    int slen = ecnt + nbkt;
    int gb = ebase + lo;
    for (int i = t; i < slen; i += 256) csr[gb + i] = (ushort)slice[i];
}

// ---------------- encoder: h = x @ W_enc + b; also hd0 = bf16(dis*h) ----------------

__global__ void k_encoder(const float* __restrict__ x, const float* __restrict__ W,
                          const float* __restrict__ b, const float* __restrict__ dis,
                          float* __restrict__ h, ushort* __restrict__ hd) {
    __shared__ float Ws[FDIM * HID];
    for (int idx = threadIdx.x; idx < FDIM * HID; idx += 256) Ws[idx] = W[idx];
    __syncthreads();
    int row = blockIdx.x * 64 + (threadIdx.x >> 2);
    int c0 = (threadIdx.x & 3) * 16;
    if (row >= N_NODES) return;
    float acc[16];
#pragma unroll
    for (int j = 0; j < 16; ++j) acc[j] = b[c0 + j];
    const float4* xr = (const float4*)(x + (size_t)row * FDIM);
    for (int k4 = 0; k4 < FDIM / 4; ++k4) {
        float4 xv = xr[k4];
        const float* wr = Ws + (k4 * 4) * HID + c0;
#pragma unroll
        for (int j = 0; j < 16; ++j) acc[j] = fmaf(xv.x, wr[j], acc[j]);
#pragma unroll
        for (int j = 0; j < 16; ++j) acc[j] = fmaf(xv.y, wr[HID + j], acc[j]);
#pragma unroll
        for (int j = 0; j < 16; ++j) acc[j] = fmaf(xv.z, wr[2 * HID + j], acc[j]);
#pragma unroll
        for (int j = 0; j < 16; ++j) acc[j] = fmaf(xv.w, wr[3 * HID + j], acc[j]);
    }
    float d = dis[row];
    float* hr = h + (size_t)row * HID + c0;
    ushort* hdr = hd + (size_t)row * HID + c0;
#pragma unroll
    for (int j = 0; j < 16; ++j) {
        hr[j] = acc[j];
        __hip_bfloat16 t = __float2bfloat16(d * acc[j]);
        hdr[j] = *(ushort*)&t;
    }
}

// ---------------- gathers (clamped unroll-8: always 8 loads in flight) ----------------

// minhash: one wave per node, lane = uint chunk. 12500 blocks x 4 nodes.
__global__ void __launch_bounds__(256) k_mh(const int* __restrict__ offsets,
                     const ushort* __restrict__ csr, const uint* __restrict__ mhin,
                     uint* __restrict__ out_p, float* __restrict__ out_f) {
    int node = blockIdx.x * 4 + (threadIdx.x >> 6);
    int l = threadIdx.x & 63;
    int s = offsets[node], e = offsets[node + 1];
    uint mn0 = 0xFFFFu, mn1 = 0xFFFFu, mn2 = 0xFFFFu, mn3 = 0xFFFFu;
    for (int p = s; p < e; p += 8) {
        int q1 = p + 1, q2 = p + 2, q3 = p + 3, q4 = p + 4, q5 = p + 5, q6 = p + 6, q7 = p + 7;
        uint j0 = csr[p];
        uint j1 = csr[q1 < e ? q1 : p];
        uint j2 = csr[q2 < e ? q2 : p];
        uint j3 = csr[q3 < e ? q3 : p];
        uint j4 = csr[q4 < e ? q4 : p];
        uint j5 = csr[q5 < e ? q5 : p];
        uint j6 = csr[q6 < e ? q6 : p];
        uint j7 = csr[q7 < e ? q7 : p];
        uint a0 = mhin[(size_t)j0 * 64 + l];
        uint a1 = mhin[(size_t)j1 * 64 + l];
        uint a2 = mhin[(size_t)j2 * 64 + l];
        uint a3 = mhin[(size_t)j3 * 64 + l];
        uint a4 = mhin[(size_t)j4 * 64 + l];
        uint a5 = mhin[(size_t)j5 * 64 + l];
        uint a6 = mhin[(size_t)j6 * 64 + l];
        uint a7 = mhin[(size_t)j7 * 64 + l];
        mn0 = min(mn0, min(a0 & 0xFFFFu, a1 & 0xFFFFu));
        mn1 = min(mn1, min(a0 >> 16, a1 >> 16));
        mn2 = min(mn2, min(a2 & 0xFFFFu, a3 & 0xFFFFu));
        mn3 = min(mn3, min(a2 >> 16, a3 >> 16));
        mn0 = min(mn0, min(a4 & 0xFFFFu, a5 & 0xFFFFu));
        mn1 = min(mn1, min(a4 >> 16, a5 >> 16));
        mn2 = min(mn2, min(a6 & 0xFFFFu, a7 & 0xFFFFu));
        mn3 = min(mn3, min(a6 >> 16, a7 >> 16));
    }
    mn0 = min(mn0, mn2); mn1 = min(mn1, mn3);
    if (out_p) {
        out_p[(size_t)node * 64 + l] = mn0 | (mn1 << 16);
    } else {
        float2 w;
        w.x = __uint_as_float(mn0 << 16);
        w.y = __uint_as_float(mn1 << 16);
        *(float2*)(out_f + (size_t)node * NPERM + 2 * l) = w;
    }
}

// HLL: 16 lanes per node (4 packed regs/lane), 16 nodes per block. 3125 blocks.
__global__ void __launch_bounds__(256) k_hll(const int* __restrict__ offsets,
                      const ushort* __restrict__ csr, const uint* __restrict__ hin,
                      uint* __restrict__ hout_p, float* __restrict__ hout_f,
                      float* __restrict__ cards, int kcol) {
    int node = blockIdx.x * 16 + (threadIdx.x >> 4);
    int q = threadIdx.x & 15;
    int s = offsets[node], e = offsets[node + 1];
    uint m0 = 0, m1 = 0, m2 = 0, m3 = 0;
#define HLL_ACC(vv) do { uint _v = (vv); \
        m0 = max(m0, _v & 0xFFu); m1 = max(m1, (_v >> 8) & 0xFFu); \
        m2 = max(m2, (_v >> 16) & 0xFFu); m3 = max(m3, _v >> 24); } while (0)
    for (int p = s; p < e; p += 8) {
        int q1 = p + 1, q2 = p + 2, q3 = p + 3, q4 = p + 4, q5 = p + 5, q6 = p + 6, q7 = p + 7;
        uint j0 = csr[p];
        uint j1 = csr[q1 < e ? q1 : p];
        uint j2 = csr[q2 < e ? q2 : p];
        uint j3 = csr[q3 < e ? q3 : p];
        uint j4 = csr[q4 < e ? q4 : p];
        uint j5 = csr[q5 < e ? q5 : p];
        uint j6 = csr[q6 < e ? q6 : p];
        uint j7 = csr[q7 < e ? q7 : p];
        uint a0 = hin[(size_t)j0 * 16 + q];
        uint a1 = hin[(size_t)j1 * 16 + q];
        uint a2 = hin[(size_t)j2 * 16 + q];
        uint a3 = hin[(size_t)j3 * 16 + q];
        uint a4 = hin[(size_t)j4 * 16 + q];
        uint a5 = hin[(size_t)j5 * 16 + q];
        uint a6 = hin[(size_t)j6 * 16 + q];
        uint a7 = hin[(size_t)j7 * 16 + q];
        HLL_ACC(a0); HLL_ACC(a1); HLL_ACC(a2); HLL_ACC(a3);
        HLL_ACC(a4); HLL_ACC(a5); HLL_ACC(a6); HLL_ACC(a7);
    }
#undef HLL_ACC
    if (hout_p) hout_p[(size_t)node * 16 + q] = m0 | (m1 << 8) | (m2 << 16) | (m3 << 24);
    if (hout_f) {
        float4 w = {(float)m0, (float)m1, (float)m2, (float)m3};
        *(float4*)(hout_f + (size_t)node * HLLM + 4 * q) = w;
    }
    float v = exp2f(-(float)m0) + exp2f(-(float)m1) + exp2f(-(float)m2) + exp2f(-(float)m3);
    v += __shfl_xor(v, 1); v += __shfl_xor(v, 2);
    v += __shfl_xor(v, 4); v += __shfl_xor(v, 8);
    if (q == 0) {
        const float alphamm = (float)(0.7213 / (1.0 + 1.079 / 64.0) * 64.0 * 64.0);
        cards[(size_t)node * 2 + kcol] = alphamm / v;
    }
}

// ---------------- fused GCN layer (gather-sum then matvec via linearity) ----------------
// h_out[i] = h_in[i] + b + dis_i * ( (sum_j hd_j) @ W ),  hd_j = bf16(dis_j * h_j)
// One wave per node (4 nodes/wave sequential), 16 nodes/block, 3125 blocks exact.

__global__ void __launch_bounds__(256) k_gcn(const int* __restrict__ offsets,
                      const ushort* __restrict__ csr, const ushort* __restrict__ hd,
                      const float* __restrict__ W, const float* __restrict__ b,
                      const float* __restrict__ dis, const float* __restrict__ h_in,
                      float* __restrict__ h_out, ushort* __restrict__ hd_out) {
    __shared__ float Ws[HID * HID];
    int t = threadIdx.x;
    for (int i = t; i < HID * HID; i += 256) Ws[i] = W[i];
    __syncthreads();
    int wid = t >> 6, c = t & 63;
    int base = blockIdx.x * 16 + wid * 4;
    for (int n = 0; n < 4; ++n) {
        int node = base + n;
        int s = offsets[node], e = offsets[node + 1];
        float acc0 = 0.f, acc1 = 0.f;
        for (int p = s; p < e; p += 8) {
            int q1 = p + 1, q2 = p + 2, q3 = p + 3, q4 = p + 4, q5 = p + 5, q6 = p + 6, q7 = p + 7;
            bool v1 = q1 < e, v2 = q2 < e, v3 = q3 < e, v4 = q4 < e, v5 = q5 < e, v6 = q6 < e, v7 = q7 < e;
            uint j0 = csr[p];
            uint j1 = csr[v1 ? q1 : p];
            uint j2 = csr[v2 ? q2 : p];
            uint j3 = csr[v3 ? q3 : p];
            uint j4 = csr[v4 ? q4 : p];
            uint j5 = csr[v5 ? q5 : p];
            uint j6 = csr[v6 ? q6 : p];
            uint j7 = csr[v7 ? q7 : p];
            uint a0 = hd[(size_t)j0 * HID + c];
            uint a1 = hd[(size_t)j1 * HID + c];
            uint a2 = hd[(size_t)j2 * HID + c];
            uint a3 = hd[(size_t)j3 * HID + c];
            uint a4 = hd[(size_t)j4 * HID + c];
            uint a5 = hd[(size_t)j5 * HID + c];
            uint a6 = hd[(size_t)j6 * HID + c];
            uint a7 = hd[(size_t)j7 * HID + c];
            acc0 += __uint_as_float(a0 << 16);
            acc0 += v1 ? __uint_as_float(a1 << 16) : 0.f;
            acc1 += v2 ? __uint_as_float(a2 << 16) : 0.f;
            acc1 += v3 ? __uint_as_float(a3 << 16) : 0.f;
            acc0 += v4 ? __uint_as_float(a4 << 16) : 0.f;
            acc0 += v5 ? __uint_as_float(a5 << 16) : 0.f;
            acc1 += v6 ? __uint_as_float(a6 << 16) : 0.f;
            acc1 += v7 ? __uint_as_float(a7 << 16) : 0.f;
        }
        float sc = acc0 + acc1;   // lane c holds channel-c sum
        float o = 0.f;
#pragma unroll
        for (int k = 0; k < HID; ++k)
            o = fmaf(__shfl(sc, k, 64), Ws[k * HID + c], o);
        float d = dis[node];
        float res = h_in[(size_t)node * HID + c] + b[c] + d * o;
        h_out[(size_t)node * HID + c] = res;
        if (hd_out) {
            __hip_bfloat16 hb = __float2bfloat16(d * res);
            hd_out[(size_t)node * HID + c] = *(ushort*)&hb;
        }
    }
}

// ---------------- driver ----------------

static inline char* align256(char* p) {
    return (char*)(((uintptr_t)p + 255) & ~(uintptr_t)255);
}

extern "C" void kernel_launch(void* const* d_in, const int* in_sizes, int n_in,
                              void* d_out, int out_size, void* d_ws, size_t ws_size,
                              hipStream_t stream) {
    const float* x       = (const float*)d_in[0];
    const int*   ei      = (const int*)d_in[1];
    const int*   mh0     = (const int*)d_in[2];
    const int*   hll0    = (const int*)d_in[3];
    const float* W_enc   = (const float*)d_in[4];
    const float* b_enc   = (const float*)d_in[5];
    const float* W_convs = (const float*)d_in[6];
    const float* b_convs = (const float*)d_in[7];

    float* out       = (float*)d_out;
    float* out_h     = out;
    float* out_cards = out + (size_t)N_NODES * HID;
    float* out_mh    = out_cards + (size_t)N_NODES * 2;
    float* out_hll   = out_mh + (size_t)N_NODES * NPERM;

    char* w = (char*)d_ws;
    int*   hist2d  = (int*)w;   w = align256(w + (size_t)HIST_BLOCKS * NBUCK * 4);
    int*   bktcnt  = (int*)w;   w = align256(w + (size_t)NBUCK * 4);
    int*   gbase   = (int*)w;   w = align256(w + (size_t)NBUCK * 4);
    int*   gcur    = (int*)w;   w = align256(w + (size_t)NBUCK * 4);
    int*   offsets = (int*)w;   w = align256(w + (size_t)(N_NODES + 1) * 4);
    float* dis     = (float*)w; w = align256(w + (size_t)N_NODES * 4);
    ushort* csr    = (ushort*)w; w = align256(w + (size_t)(N_EDGES + N_NODES) * 2);
    uint*  mhp0    = (uint*)w;  w = align256(w + (size_t)N_NODES * 64 * 4);
    uint*  mhA     = (uint*)w;  w = align256(w + (size_t)N_NODES * 64 * 4);
    uint*  hp0     = (uint*)w;  w = align256(w + (size_t)N_NODES * 16 * 4);
    uint*  hllA    = (uint*)w;  w = align256(w + (size_t)N_NODES * 16 * 4);
    float* h_cur   = (float*)w; w = align256(w + (size_t)N_NODES * HID * 4);
    ushort* hd0    = (ushort*)w; w = align256(w + (size_t)N_NODES * HID * 2);
    ushort* hd1    = (ushort*)w; w = align256(w + (size_t)N_NODES * HID * 2);
    uint*  ebuf    = mhA;  // build-phase only; mhA first written after k_csr consumed ebuf

    const int* src = ei;
    const int* dst = ei + N_EDGES;

    k_prep<<<MH_BLOCKS + HLL_BLOCKS + HIST_BLOCKS, 256, 0, stream>>>(mh0, mhp0, hll0, hp0, dst, hist2d);
    k_bktscan<<<1, 256, 0, stream>>>(hist2d, bktcnt, gbase, gcur, offsets);
    k_scatter<<<SCAT_BLOCKS, 256, 0, stream>>>(src, dst, gcur, ebuf);
    k_csr<<<NBUCK, 256, 0, stream>>>(ebuf, gbase, bktcnt, offsets, dis, csr);
    k_encoder<<<(N_NODES + 63) / 64, 256, 0, stream>>>(x, W_enc, b_enc, dis, h_cur, hd0);

    // ---- hop 0 ----
    k_hll<<<HLL_BLOCKS, 256, 0, stream>>>(offsets, csr, hp0, hllA, nullptr, out_cards, 0);
    k_mh<<<MH_BLOCKS / 1, 256, 0, stream>>>(offsets, csr, mhp0, mhA, nullptr);
    k_gcn<<<3125, 256, 0, stream>>>(offsets, csr, hd0, W_convs, b_convs, dis, h_cur, h_cur, hd1);

    // ---- hop 1 ----
    k_hll<<<HLL_BLOCKS, 256, 0, stream>>>(offsets, csr, hllA, nullptr, out_hll, out_cards, 1);
    k_mh<<<MH_BLOCKS / 1, 256, 0, stream>>>(offsets, csr, mhA, nullptr, out_mh);
    k_gcn<<<3125, 256, 0, stream>>>(offsets, csr, hd1, W_convs + HID * HID, b_convs + HID, dis, h_cur, out_h, nullptr);
}

// Round 8
// 224.484 us; speedup vs baseline: 1.6950x; 1.3914x over previous
//
#include <hip/hip_runtime.h>
#include <hip/hip_bf16.h>

typedef unsigned int uint;
typedef unsigned short ushort;

#define N_NODES 50000
#define N_EDGES 800000
#define FDIM 128
#define HID 64
#define NPERM 128
#define HLLM 64

#define BSHIFT 8
#define BNODES 256                 // nodes per bucket
#define NBUCK 196                  // ceil(50000/256)
#define SCAT_BLOCKS 256
#define EDGES_PER_BLK 3125         // 800000/256 exactly
#define HIST_BLOCKS 64
#define EDGES_PER_HIST 12500       // 800000/64 exactly
#define MH_BLOCKS 12500            // 50000*64/256 (pack)
#define HLL_BLOCKS 3125            // 50000*16/256 (pack)
#define SLICE_CAP 6400
#define CONV_BLOCKS 782            // ceil(50000/64)

// ---------------- prep: pack hashes + dst histogram ----------------

__global__ void k_prep(const int* __restrict__ mh, uint* __restrict__ mhp,
                       const int* __restrict__ hll, uint* __restrict__ hp,
                       const int* __restrict__ dst, int* __restrict__ hist2d) {
    int b = blockIdx.x;
    if (b < MH_BLOCKS) {
        // minhash int32 -> top16(float32) u16 (monotone, err <= |v|/256)
        int i = b * 256 + threadIdx.x;
        int2 v = ((const int2*)mh)[i];
        uint u0 = __float_as_uint((float)v.x) >> 16;
        uint u1 = __float_as_uint((float)v.y) >> 16;
        mhp[i] = u0 | (u1 << 16);
    } else if (b < MH_BLOCKS + HLL_BLOCKS) {
        // hll int32 (<20; max-only keeps <256) -> u8 packed
        int i = (b - MH_BLOCKS) * 256 + threadIdx.x;
        int4 v = ((const int4*)hll)[i];
        hp[i] = (uint)v.x | ((uint)v.y << 8) | ((uint)v.z << 16) | ((uint)v.w << 24);
    } else {
        int hb = b - MH_BLOCKS - HLL_BLOCKS;
        __shared__ int h[NBUCK];
        for (int i = threadIdx.x; i < NBUCK; i += 256) h[i] = 0;
        __syncthreads();
        int e0 = hb * EDGES_PER_HIST;
        for (int i = threadIdx.x; i < EDGES_PER_HIST; i += 256)
            atomicAdd(&h[dst[e0 + i] >> BSHIFT], 1);
        __syncthreads();
        for (int i = threadIdx.x; i < NBUCK; i += 256)
            hist2d[hb * NBUCK + i] = h[i];
    }
}

// reduce per-block hists -> bktcnt, exclusive scan -> gbase/gcur
__global__ void k_bktscan(const int* __restrict__ hist2d, int* __restrict__ bktcnt,
                          int* __restrict__ gbase, int* __restrict__ gcur,
                          int* __restrict__ offsets) {
    __shared__ int s[256];
    int t = threadIdx.x;
    int v = 0;
    if (t < NBUCK)
        for (int k = 0; k < HIST_BLOCKS; ++k) v += hist2d[k * NBUCK + t];
    s[t] = v;
    __syncthreads();
    for (int off = 1; off < 256; off <<= 1) {
        int u = (t >= off) ? s[t - off] : 0;
        __syncthreads();
        s[t] += u;
        __syncthreads();
    }
    if (t < NBUCK) {
        int ex = s[t] - v;
        bktcnt[t] = v; gbase[t] = ex; gcur[t] = ex;
    }
    if (t == 0) offsets[N_NODES] = N_EDGES + N_NODES;
}

// ---------------- pass A: block-local multisplit scatter ----------------

__global__ void __launch_bounds__(256) k_scatter(const int* __restrict__ src,
                          const int* __restrict__ dst,
                          int* __restrict__ gcur, uint* __restrict__ ebuf) {
    __shared__ uint ecache[EDGES_PER_BLK];
    __shared__ int cnt[NBUCK];
    __shared__ int cur[NBUCK];
    int t = threadIdx.x;
    for (int i = t; i < NBUCK; i += 256) cnt[i] = 0;
    __syncthreads();
    int e0 = blockIdx.x * EDGES_PER_BLK;
    for (int i = t; i < EDGES_PER_BLK; i += 256) {
        int d = dst[e0 + i];
        int s = src[e0 + i];
        ecache[i] = ((uint)s << 16) | (uint)d;   // both < 65536
        atomicAdd(&cnt[d >> BSHIFT], 1);
    }
    __syncthreads();
    for (int b = t; b < NBUCK; b += 256)
        cur[b] = atomicAdd(&gcur[b], cnt[b]);
    __syncthreads();
    for (int i = t; i < EDGES_PER_BLK; i += 256) {
        uint en = ecache[i];
        uint d = en & 0xFFFFu;
        int p = atomicAdd(&cur[d >> BSHIFT], 1);
        ebuf[p] = ((en >> 16) << BSHIFT) | (d & (BNODES - 1));
    }
}

// ---------------- pass B: build CSR slice (u16) in LDS; emit offsets/dis ----------------

__global__ void __launch_bounds__(256) k_csr(const uint* __restrict__ ebuf,
                      const int* __restrict__ gbase, const int* __restrict__ bktcnt,
                      int* __restrict__ offsets, float* __restrict__ dis,
                      ushort* __restrict__ csr) {
    __shared__ int lcur[BNODES];
    __shared__ int ssum[256];
    __shared__ uint slice[SLICE_CAP];
    int b = blockIdx.x;
    int lo = b << BSHIFT;
    int nbkt = min(BNODES, N_NODES - lo);
    int ebase = gbase[b];
    int ecnt = bktcnt[b];
    int t = threadIdx.x;
    lcur[t] = 0;
    __syncthreads();
    for (int i = t; i < ecnt; i += 256)
        atomicAdd(&lcur[ebuf[ebase + i] & (BNODES - 1)], 1);
    __syncthreads();
    int a0 = lcur[t];
    ssum[t] = a0;
    __syncthreads();
    for (int off = 1; off < 256; off <<= 1) {
        int u = (t >= off) ? ssum[t - off] : 0;
        __syncthreads();
        ssum[t] += u;
        __syncthreads();
    }
    int pre = ssum[t] - a0;
    if (t < nbkt) {
        int st = pre + t;
        slice[st] = (uint)(lo + t);       // self-loop first
        lcur[t] = st + 1;
        offsets[lo + t] = ebase + lo + st;
        dis[lo + t] = rsqrtf((float)(a0 + 1));
    }
    __syncthreads();
    for (int i = t; i < ecnt; i += 256) {
        uint en = ebuf[ebase + i];
        int p = atomicAdd(&lcur[en & (BNODES - 1)], 1);
        slice[p] = en >> BSHIFT;
    }
    __syncthreads();
    int slen = ecnt + nbkt;
    int gb = ebase + lo;
    for (int i = t; i < slen; i += 256) csr[gb + i] = (ushort)slice[i];
}

// ---------------- encoder: h = x @ W_enc + b ----------------

__global__ void k_encoder(const float* __restrict__ x, const float* __restrict__ W,
                          const float* __restrict__ b, float* __restrict__ h) {
    __shared__ float Ws[FDIM * HID];
    for (int idx = threadIdx.x; idx < FDIM * HID; idx += 256) Ws[idx] = W[idx];
    __syncthreads();
    int row = blockIdx.x * 64 + (threadIdx.x >> 2);
    int c0 = (threadIdx.x & 3) * 16;
    if (row >= N_NODES) return;
    float acc[16];
#pragma unroll
    for (int j = 0; j < 16; ++j) acc[j] = b[c0 + j];
    const float4* xr = (const float4*)(x + (size_t)row * FDIM);
    for (int k4 = 0; k4 < FDIM / 4; ++k4) {
        float4 xv = xr[k4];
        const float* wr = Ws + (k4 * 4) * HID + c0;
#pragma unroll
        for (int j = 0; j < 16; ++j) acc[j] = fmaf(xv.x, wr[j], acc[j]);
#pragma unroll
        for (int j = 0; j < 16; ++j) acc[j] = fmaf(xv.y, wr[HID + j], acc[j]);
#pragma unroll
        for (int j = 0; j < 16; ++j) acc[j] = fmaf(xv.z, wr[2 * HID + j], acc[j]);
#pragma unroll
        for (int j = 0; j < 16; ++j) acc[j] = fmaf(xv.w, wr[3 * HID + j], acc[j]);
    }
    float* hr = h + (size_t)row * HID + c0;
#pragma unroll
    for (int j = 0; j < 16; ++j) hr[j] = acc[j];
}

// ---------------- fat per-hop kernel: HLL gather | MH gather | convmm ----------------
// blocks [0, HLL_BLOCKS): hll    blocks [HLL_BLOCKS, +MH_BLOCKS): mh
// blocks [HLL_BLOCKS+MH_BLOCKS, +CONV_BLOCKS): hWs = bf16(dis*(h@W))

__global__ void __launch_bounds__(256) k_hop(const int* __restrict__ offsets,
                    const ushort* __restrict__ csr,
                    const uint* __restrict__ hll_in, uint* __restrict__ hll_out_p,
                    float* __restrict__ hll_out_f, float* __restrict__ cards, int kcol,
                    const uint* __restrict__ mh_in, uint* __restrict__ mh_out_p,
                    float* __restrict__ mh_out_f,
                    const float* __restrict__ h, const float* __restrict__ W,
                    const float* __restrict__ dis, ushort* __restrict__ hWs) {
    int blk = blockIdx.x;
    if (blk < HLL_BLOCKS) {
        // ---- HLL: 16 lanes/node, packed u8 regs ----
        int node = blk * 16 + (threadIdx.x >> 4);
        int q = threadIdx.x & 15;
        int s = offsets[node], e = offsets[node + 1];
        uint m0 = 0, m1 = 0, m2 = 0, m3 = 0;
#define HLL_ACC(vv) do { uint _v = (vv); \
        m0 = max(m0, _v & 0xFFu); m1 = max(m1, (_v >> 8) & 0xFFu); \
        m2 = max(m2, (_v >> 16) & 0xFFu); m3 = max(m3, _v >> 24); } while (0)
        for (int p = s; p < e; p += 8) {
            int q1 = p + 1, q2 = p + 2, q3 = p + 3, q4 = p + 4, q5 = p + 5, q6 = p + 6, q7 = p + 7;
            uint j0 = csr[p];
            uint j1 = csr[q1 < e ? q1 : p];
            uint j2 = csr[q2 < e ? q2 : p];
            uint j3 = csr[q3 < e ? q3 : p];
            uint j4 = csr[q4 < e ? q4 : p];
            uint j5 = csr[q5 < e ? q5 : p];
            uint j6 = csr[q6 < e ? q6 : p];
            uint j7 = csr[q7 < e ? q7 : p];
            uint a0 = hll_in[(size_t)j0 * 16 + q];
            uint a1 = hll_in[(size_t)j1 * 16 + q];
            uint a2 = hll_in[(size_t)j2 * 16 + q];
            uint a3 = hll_in[(size_t)j3 * 16 + q];
            uint a4 = hll_in[(size_t)j4 * 16 + q];
            uint a5 = hll_in[(size_t)j5 * 16 + q];
            uint a6 = hll_in[(size_t)j6 * 16 + q];
            uint a7 = hll_in[(size_t)j7 * 16 + q];
            HLL_ACC(a0); HLL_ACC(a1); HLL_ACC(a2); HLL_ACC(a3);
            HLL_ACC(a4); HLL_ACC(a5); HLL_ACC(a6); HLL_ACC(a7);
        }
#undef HLL_ACC
        if (hll_out_p) hll_out_p[(size_t)node * 16 + q] = m0 | (m1 << 8) | (m2 << 16) | (m3 << 24);
        if (hll_out_f) {
            float4 w = {(float)m0, (float)m1, (float)m2, (float)m3};
            *(float4*)(hll_out_f + (size_t)node * HLLM + 4 * q) = w;
        }
        float v = exp2f(-(float)m0) + exp2f(-(float)m1) + exp2f(-(float)m2) + exp2f(-(float)m3);
        v += __shfl_xor(v, 1); v += __shfl_xor(v, 2);
        v += __shfl_xor(v, 4); v += __shfl_xor(v, 8);
        if (q == 0) {
            const float alphamm = (float)(0.7213 / (1.0 + 1.079 / 64.0) * 64.0 * 64.0);
            cards[(size_t)node * 2 + kcol] = alphamm / v;
        }
    } else if (blk < HLL_BLOCKS + MH_BLOCKS) {
        // ---- minhash: one wave/node, lane = uint chunk ----
        int b = blk - HLL_BLOCKS;
        int node = b * 4 + (threadIdx.x >> 6);
        int l = threadIdx.x & 63;
        int s = offsets[node], e = offsets[node + 1];
        uint mn0 = 0xFFFFu, mn1 = 0xFFFFu, mn2 = 0xFFFFu, mn3 = 0xFFFFu;
        for (int p = s; p < e; p += 8) {
            int q1 = p + 1, q2 = p + 2, q3 = p + 3, q4 = p + 4, q5 = p + 5, q6 = p + 6, q7 = p + 7;
            uint j0 = csr[p];
            uint j1 = csr[q1 < e ? q1 : p];
            uint j2 = csr[q2 < e ? q2 : p];
            uint j3 = csr[q3 < e ? q3 : p];
            uint j4 = csr[q4 < e ? q4 : p];
            uint j5 = csr[q5 < e ? q5 : p];
            uint j6 = csr[q6 < e ? q6 : p];
            uint j7 = csr[q7 < e ? q7 : p];
            uint a0 = mh_in[(size_t)j0 * 64 + l];
            uint a1 = mh_in[(size_t)j1 * 64 + l];
            uint a2 = mh_in[(size_t)j2 * 64 + l];
            uint a3 = mh_in[(size_t)j3 * 64 + l];
            uint a4 = mh_in[(size_t)j4 * 64 + l];
            uint a5 = mh_in[(size_t)j5 * 64 + l];
            uint a6 = mh_in[(size_t)j6 * 64 + l];
            uint a7 = mh_in[(size_t)j7 * 64 + l];
            mn0 = min(mn0, min(a0 & 0xFFFFu, a1 & 0xFFFFu));
            mn1 = min(mn1, min(a0 >> 16, a1 >> 16));
            mn2 = min(mn2, min(a2 & 0xFFFFu, a3 & 0xFFFFu));
            mn3 = min(mn3, min(a2 >> 16, a3 >> 16));
            mn0 = min(mn0, min(a4 & 0xFFFFu, a5 & 0xFFFFu));
            mn1 = min(mn1, min(a4 >> 16, a5 >> 16));
            mn2 = min(mn2, min(a6 & 0xFFFFu, a7 & 0xFFFFu));
            mn3 = min(mn3, min(a6 >> 16, a7 >> 16));
        }
        mn0 = min(mn0, mn2); mn1 = min(mn1, mn3);
        if (mh_out_p) {
            mh_out_p[(size_t)node * 64 + l] = mn0 | (mn1 << 16);
        } else {
            float2 w;
            w.x = __uint_as_float(mn0 << 16);
            w.y = __uint_as_float(mn1 << 16);
            *(float2*)(mh_out_f + (size_t)node * NPERM + 2 * l) = w;
        }
    } else {
        // ---- convmm: hWs = bf16(dis * (h @ W)) ----
        __shared__ float Ws[HID * HID];
        for (int i = threadIdx.x; i < HID * HID; i += 256) Ws[i] = W[i];
        __syncthreads();
        int row = (blk - HLL_BLOCKS - MH_BLOCKS) * 64 + (threadIdx.x >> 2);
        int c0 = (threadIdx.x & 3) * 16;
        if (row >= N_NODES) return;
        float acc[16] = {0.f, 0.f, 0.f, 0.f, 0.f, 0.f, 0.f, 0.f,
                         0.f, 0.f, 0.f, 0.f, 0.f, 0.f, 0.f, 0.f};
        const float4* hr = (const float4*)(h + (size_t)row * HID);
        for (int k4 = 0; k4 < HID / 4; ++k4) {
            float4 hv = hr[k4];
            const float* wr = Ws + (k4 * 4) * HID + c0;
#pragma unroll
            for (int j = 0; j < 16; ++j) acc[j] = fmaf(hv.x, wr[j], acc[j]);
#pragma unroll
            for (int j = 0; j < 16; ++j) acc[j] = fmaf(hv.y, wr[HID + j], acc[j]);
#pragma unroll
            for (int j = 0; j < 16; ++j) acc[j] = fmaf(hv.z, wr[2 * HID + j], acc[j]);
#pragma unroll
            for (int j = 0; j < 16; ++j) acc[j] = fmaf(hv.w, wr[3 * HID + j], acc[j]);
        }
        float d = dis[row];
        ushort* o = hWs + (size_t)row * HID + c0;
#pragma unroll
        for (int j = 0; j < 16; ++j) {
            __hip_bfloat16 t = __float2bfloat16(d * acc[j]);
            o[j] = *(ushort*)&t;
        }
    }
}

// ---------------- GCN aggregate (gather-sum over bf16 hWs rows) ----------------

__global__ void __launch_bounds__(256) k_agg(const int* __restrict__ offsets,
                      const ushort* __restrict__ csr, const ushort* __restrict__ hWs,
                      const float* __restrict__ dis, const float* __restrict__ b,
                      const float* __restrict__ h_in, float* __restrict__ h_out) {
    int node = blockIdx.x * 4 + (threadIdx.x >> 6);
    int c = threadIdx.x & 63;
    int s = offsets[node], e = offsets[node + 1];
    float acc0 = 0.f, acc1 = 0.f;
    for (int p = s; p < e; p += 8) {
        int q1 = p + 1, q2 = p + 2, q3 = p + 3, q4 = p + 4, q5 = p + 5, q6 = p + 6, q7 = p + 7;
        bool v1 = q1 < e, v2 = q2 < e, v3 = q3 < e, v4 = q4 < e, v5 = q5 < e, v6 = q6 < e, v7 = q7 < e;
        uint j0 = csr[p];
        uint j1 = csr[v1 ? q1 : p];
        uint j2 = csr[v2 ? q2 : p];
        uint j3 = csr[v3 ? q3 : p];
        uint j4 = csr[v4 ? q4 : p];
        uint j5 = csr[v5 ? q5 : p];
        uint j6 = csr[v6 ? q6 : p];
        uint j7 = csr[v7 ? q7 : p];
        uint a0 = hWs[(size_t)j0 * HID + c];
        uint a1 = hWs[(size_t)j1 * HID + c];
        uint a2 = hWs[(size_t)j2 * HID + c];
        uint a3 = hWs[(size_t)j3 * HID + c];
        uint a4 = hWs[(size_t)j4 * HID + c];
        uint a5 = hWs[(size_t)j5 * HID + c];
        uint a6 = hWs[(size_t)j6 * HID + c];
        uint a7 = hWs[(size_t)j7 * HID + c];
        acc0 += __uint_as_float(a0 << 16);
        acc0 += v1 ? __uint_as_float(a1 << 16) : 0.f;
        acc1 += v2 ? __uint_as_float(a2 << 16) : 0.f;
        acc1 += v3 ? __uint_as_float(a3 << 16) : 0.f;
        acc0 += v4 ? __uint_as_float(a4 << 16) : 0.f;
        acc0 += v5 ? __uint_as_float(a5 << 16) : 0.f;
        acc1 += v6 ? __uint_as_float(a6 << 16) : 0.f;
        acc1 += v7 ? __uint_as_float(a7 << 16) : 0.f;
    }
    float acc = acc0 + acc1;
    h_out[(size_t)node * HID + c] = h_in[(size_t)node * HID + c] + b[c] + dis[node] * acc;
}

// ---------------- driver ----------------

static inline char* align256(char* p) {
    return (char*)(((uintptr_t)p + 255) & ~(uintptr_t)255);
}

extern "C" void kernel_launch(void* const* d_in, const int* in_sizes, int n_in,
                              void* d_out, int out_size, void* d_ws, size_t ws_size,
                              hipStream_t stream) {
    const float* x       = (const float*)d_in[0];
    const int*   ei      = (const int*)d_in[1];
    const int*   mh0     = (const int*)d_in[2];
    const int*   hll0    = (const int*)d_in[3];
    const float* W_enc   = (const float*)d_in[4];
    const float* b_enc   = (const float*)d_in[5];
    const float* W_convs = (const float*)d_in[6];
    const float* b_convs = (const float*)d_in[7];

    float* out       = (float*)d_out;
    float* out_h     = out;
    float* out_cards = out + (size_t)N_NODES * HID;
    float* out_mh    = out_cards + (size_t)N_NODES * 2;
    float* out_hll   = out_mh + (size_t)N_NODES * NPERM;

    char* w = (char*)d_ws;
    int*   hist2d  = (int*)w;   w = align256(w + (size_t)HIST_BLOCKS * NBUCK * 4);
    int*   bktcnt  = (int*)w;   w = align256(w + (size_t)NBUCK * 4);
    int*   gbase   = (int*)w;   w = align256(w + (size_t)NBUCK * 4);
    int*   gcur    = (int*)w;   w = align256(w + (size_t)NBUCK * 4);
    int*   offsets = (int*)w;   w = align256(w + (size_t)(N_NODES + 1) * 4);
    float* dis     = (float*)w; w = align256(w + (size_t)N_NODES * 4);
    ushort* csr    = (ushort*)w; w = align256(w + (size_t)(N_EDGES + N_NODES) * 2);
    uint*  mhp0    = (uint*)w;  w = align256(w + (size_t)N_NODES * 64 * 4);
    uint*  mhA     = (uint*)w;  w = align256(w + (size_t)N_NODES * 64 * 4);
    uint*  hp0     = (uint*)w;  w = align256(w + (size_t)N_NODES * 16 * 4);
    uint*  hllA    = (uint*)w;  w = align256(w + (size_t)N_NODES * 16 * 4);
    float* h_cur   = (float*)w; w = align256(w + (size_t)N_NODES * HID * 4);
    ushort* hWs    = (ushort*)w; w = align256(w + (size_t)N_NODES * HID * 2);
    uint*  ebuf    = mhA;  // build-phase only; mhA first written after k_csr consumed ebuf

    const int* src = ei;
    const int* dst = ei + N_EDGES;

    k_prep<<<MH_BLOCKS + HLL_BLOCKS + HIST_BLOCKS, 256, 0, stream>>>(mh0, mhp0, hll0, hp0, dst, hist2d);
    k_bktscan<<<1, 256, 0, stream>>>(hist2d, bktcnt, gbase, gcur, offsets);
    k_scatter<<<SCAT_BLOCKS, 256, 0, stream>>>(src, dst, gcur, ebuf);
    k_csr<<<NBUCK, 256, 0, stream>>>(ebuf, gbase, bktcnt, offsets, dis, csr);
    k_encoder<<<CONV_BLOCKS, 256, 0, stream>>>(x, W_enc, b_enc, h_cur);

    // ---- hop 0: hll | mh | convmm fused dispatch, then aggregate ----
    k_hop<<<HLL_BLOCKS + MH_BLOCKS + CONV_BLOCKS, 256, 0, stream>>>(
        offsets, csr,
        hp0, hllA, nullptr, out_cards, 0,
        mhp0, mhA, nullptr,
        h_cur, W_convs, dis, hWs);
    k_agg<<<MH_BLOCKS, 256, 0, stream>>>(offsets, csr, hWs, dis, b_convs, h_cur, h_cur);

    // ---- hop 1 ----
    k_hop<<<HLL_BLOCKS + MH_BLOCKS + CONV_BLOCKS, 256, 0, stream>>>(
        offsets, csr,
        hllA, nullptr, out_hll, out_cards, 1,
        mhA, nullptr, out_mh,
        h_cur, W_convs + HID * HID, dis, hWs);
    k_agg<<<MH_BLOCKS, 256, 0, stream>>>(offsets, csr, hWs, dis, b_convs + HID, h_cur, out_h);
}

// Round 9
// 215.584 us; speedup vs baseline: 1.7650x; 1.0413x over previous
//
#include <hip/hip_runtime.h>
#include <hip/hip_bf16.h>

typedef unsigned int uint;
typedef unsigned short ushort;

#define N_NODES 50000
#define N_EDGES 800000
#define FDIM 128
#define HID 64
#define NPERM 128
#define HLLM 64

#define BSHIFT 8
#define BNODES 256                 // nodes per bucket
#define NBUCK 196                  // ceil(50000/256)
#define SCAT_BLOCKS 256
#define EDGES_PER_BLK 3125         // 800000/256 exactly
#define HIST_BLOCKS 64
#define EDGES_PER_HIST 12500       // 800000/64 exactly
#define MH_BLOCKS 12500            // 50000*4 nodes/block
#define HLL_BLOCKS 3125            // 50000*16 nodes/block
#define SLICE_CAP 6400
#define CONV_BLOCKS 782            // ceil(50000/64)

// ================= gather bodies (validated round 4/8) =================

__device__ __forceinline__ void mh_body(int node, int l, const int* __restrict__ offsets,
                                        const ushort* __restrict__ csr,
                                        const uint* __restrict__ mh_in,
                                        uint* __restrict__ out_p, float* __restrict__ out_f) {
    int s = offsets[node], e = offsets[node + 1];
    uint mn0 = 0xFFFFu, mn1 = 0xFFFFu, mn2 = 0xFFFFu, mn3 = 0xFFFFu;
    for (int p = s; p < e; p += 8) {
        int q1 = p + 1, q2 = p + 2, q3 = p + 3, q4 = p + 4, q5 = p + 5, q6 = p + 6, q7 = p + 7;
        uint j0 = csr[p];
        uint j1 = csr[q1 < e ? q1 : p];
        uint j2 = csr[q2 < e ? q2 : p];
        uint j3 = csr[q3 < e ? q3 : p];
        uint j4 = csr[q4 < e ? q4 : p];
        uint j5 = csr[q5 < e ? q5 : p];
        uint j6 = csr[q6 < e ? q6 : p];
        uint j7 = csr[q7 < e ? q7 : p];
        uint a0 = mh_in[(size_t)j0 * 64 + l];
        uint a1 = mh_in[(size_t)j1 * 64 + l];
        uint a2 = mh_in[(size_t)j2 * 64 + l];
        uint a3 = mh_in[(size_t)j3 * 64 + l];
        uint a4 = mh_in[(size_t)j4 * 64 + l];
        uint a5 = mh_in[(size_t)j5 * 64 + l];
        uint a6 = mh_in[(size_t)j6 * 64 + l];
        uint a7 = mh_in[(size_t)j7 * 64 + l];
        mn0 = min(mn0, min(a0 & 0xFFFFu, a1 & 0xFFFFu));
        mn1 = min(mn1, min(a0 >> 16, a1 >> 16));
        mn2 = min(mn2, min(a2 & 0xFFFFu, a3 & 0xFFFFu));
        mn3 = min(mn3, min(a2 >> 16, a3 >> 16));
        mn0 = min(mn0, min(a4 & 0xFFFFu, a5 & 0xFFFFu));
        mn1 = min(mn1, min(a4 >> 16, a5 >> 16));
        mn2 = min(mn2, min(a6 & 0xFFFFu, a7 & 0xFFFFu));
        mn3 = min(mn3, min(a6 >> 16, a7 >> 16));
    }
    mn0 = min(mn0, mn2); mn1 = min(mn1, mn3);
    if (out_p) {
        out_p[(size_t)node * 64 + l] = mn0 | (mn1 << 16);
    } else {
        float2 w;
        w.x = __uint_as_float(mn0 << 16);
        w.y = __uint_as_float(mn1 << 16);
        *(float2*)(out_f + (size_t)node * NPERM + 2 * l) = w;
    }
}

__device__ __forceinline__ void hll_body(int node, int q, const int* __restrict__ offsets,
                                         const ushort* __restrict__ csr,
                                         const uint* __restrict__ hll_in,
                                         uint* __restrict__ out_p, float* __restrict__ out_f,
                                         float* __restrict__ cards, int kcol) {
    int s = offsets[node], e = offsets[node + 1];
    uint m0 = 0, m1 = 0, m2 = 0, m3 = 0;
#define HLL_ACC(vv) do { uint _v = (vv); \
        m0 = max(m0, _v & 0xFFu); m1 = max(m1, (_v >> 8) & 0xFFu); \
        m2 = max(m2, (_v >> 16) & 0xFFu); m3 = max(m3, _v >> 24); } while (0)
    for (int p = s; p < e; p += 8) {
        int q1 = p + 1, q2 = p + 2, q3 = p + 3, q4 = p + 4, q5 = p + 5, q6 = p + 6, q7 = p + 7;
        uint j0 = csr[p];
        uint j1 = csr[q1 < e ? q1 : p];
        uint j2 = csr[q2 < e ? q2 : p];
        uint j3 = csr[q3 < e ? q3 : p];
        uint j4 = csr[q4 < e ? q4 : p];
        uint j5 = csr[q5 < e ? q5 : p];
        uint j6 = csr[q6 < e ? q6 : p];
        uint j7 = csr[q7 < e ? q7 : p];
        uint a0 = hll_in[(size_t)j0 * 16 + q];
        uint a1 = hll_in[(size_t)j1 * 16 + q];
        uint a2 = hll_in[(size_t)j2 * 16 + q];
        uint a3 = hll_in[(size_t)j3 * 16 + q];
        uint a4 = hll_in[(size_t)j4 * 16 + q];
        uint a5 = hll_in[(size_t)j5 * 16 + q];
        uint a6 = hll_in[(size_t)j6 * 16 + q];
        uint a7 = hll_in[(size_t)j7 * 16 + q];
        HLL_ACC(a0); HLL_ACC(a1); HLL_ACC(a2); HLL_ACC(a3);
        HLL_ACC(a4); HLL_ACC(a5); HLL_ACC(a6); HLL_ACC(a7);
    }
#undef HLL_ACC
    if (out_p) out_p[(size_t)node * 16 + q] = m0 | (m1 << 8) | (m2 << 16) | (m3 << 24);
    if (out_f) {
        float4 w = {(float)m0, (float)m1, (float)m2, (float)m3};
        *(float4*)(out_f + (size_t)node * HLLM + 4 * q) = w;
    }
    float v = exp2f(-(float)m0) + exp2f(-(float)m1) + exp2f(-(float)m2) + exp2f(-(float)m3);
    v += __shfl_xor(v, 1); v += __shfl_xor(v, 2);
    v += __shfl_xor(v, 4); v += __shfl_xor(v, 8);
    if (q == 0) {
        const float alphamm = (float)(0.7213 / (1.0 + 1.079 / 64.0) * 64.0 * 64.0);
        cards[(size_t)node * 2 + kcol] = alphamm / v;
    }
}

__device__ __forceinline__ void agg_body(int node, int c, const int* __restrict__ offsets,
                                         const ushort* __restrict__ csr,
                                         const ushort* __restrict__ hWs,
                                         const float* __restrict__ dis,
                                         const float* __restrict__ b,
                                         const float* __restrict__ h_in,
                                         float* __restrict__ h_out) {
    int s = offsets[node], e = offsets[node + 1];
    float acc0 = 0.f, acc1 = 0.f;
    for (int p = s; p < e; p += 8) {
        int q1 = p + 1, q2 = p + 2, q3 = p + 3, q4 = p + 4, q5 = p + 5, q6 = p + 6, q7 = p + 7;
        bool v1 = q1 < e, v2 = q2 < e, v3 = q3 < e, v4 = q4 < e, v5 = q5 < e, v6 = q6 < e, v7 = q7 < e;
        uint j0 = csr[p];
        uint j1 = csr[v1 ? q1 : p];
        uint j2 = csr[v2 ? q2 : p];
        uint j3 = csr[v3 ? q3 : p];
        uint j4 = csr[v4 ? q4 : p];
        uint j5 = csr[v5 ? q5 : p];
        uint j6 = csr[v6 ? q6 : p];
        uint j7 = csr[v7 ? q7 : p];
        uint a0 = hWs[(size_t)j0 * HID + c];
        uint a1 = hWs[(size_t)j1 * HID + c];
        uint a2 = hWs[(size_t)j2 * HID + c];
        uint a3 = hWs[(size_t)j3 * HID + c];
        uint a4 = hWs[(size_t)j4 * HID + c];
        uint a5 = hWs[(size_t)j5 * HID + c];
        uint a6 = hWs[(size_t)j6 * HID + c];
        uint a7 = hWs[(size_t)j7 * HID + c];
        acc0 += __uint_as_float(a0 << 16);
        acc0 += v1 ? __uint_as_float(a1 << 16) : 0.f;
        acc1 += v2 ? __uint_as_float(a2 << 16) : 0.f;
        acc1 += v3 ? __uint_as_float(a3 << 16) : 0.f;
        acc0 += v4 ? __uint_as_float(a4 << 16) : 0.f;
        acc0 += v5 ? __uint_as_float(a5 << 16) : 0.f;
        acc1 += v6 ? __uint_as_float(a6 << 16) : 0.f;
        acc1 += v7 ? __uint_as_float(a7 << 16) : 0.f;
    }
    float acc = acc0 + acc1;
    h_out[(size_t)node * HID + c] = h_in[(size_t)node * HID + c] + b[c] + dis[node] * acc;
}

__device__ __forceinline__ void convmm_body(int row, int c0, const float* __restrict__ h,
                                            const float* __restrict__ Ws,
                                            const float* __restrict__ dis,
                                            ushort* __restrict__ hWs) {
    float acc[16] = {0.f, 0.f, 0.f, 0.f, 0.f, 0.f, 0.f, 0.f,
                     0.f, 0.f, 0.f, 0.f, 0.f, 0.f, 0.f, 0.f};
    const float4* hr = (const float4*)(h + (size_t)row * HID);
    for (int k4 = 0; k4 < HID / 4; ++k4) {
        float4 hv = hr[k4];
        const float* wr = Ws + (k4 * 4) * HID + c0;
#pragma unroll
        for (int j = 0; j < 16; ++j) acc[j] = fmaf(hv.x, wr[j], acc[j]);
#pragma unroll
        for (int j = 0; j < 16; ++j) acc[j] = fmaf(hv.y, wr[HID + j], acc[j]);
#pragma unroll
        for (int j = 0; j < 16; ++j) acc[j] = fmaf(hv.z, wr[2 * HID + j], acc[j]);
#pragma unroll
        for (int j = 0; j < 16; ++j) acc[j] = fmaf(hv.w, wr[3 * HID + j], acc[j]);
    }
    float d = dis[row];
    ushort* o = hWs + (size_t)row * HID + c0;
#pragma unroll
    for (int j = 0; j < 16; ++j) {
        __hip_bfloat16 t = __float2bfloat16(d * acc[j]);
        o[j] = *(ushort*)&t;
    }
}

// ================= prep: encoder | pack mh | pack hll | hist =================
// blocks: [0,CONV) encoder; [+MH) mh pack; [+HLL) hll pack; [+HIST) histogram

__global__ void __launch_bounds__(256) k_prep(const float* __restrict__ x,
                       const float* __restrict__ W_enc, const float* __restrict__ b_enc,
                       float* __restrict__ h,
                       const int* __restrict__ mh, uint* __restrict__ mhp,
                       const int* __restrict__ hll, uint* __restrict__ hp,
                       const int* __restrict__ dst, int* __restrict__ hist2d) {
    __shared__ float smem[FDIM * HID];
    int b = blockIdx.x;
    if (b < CONV_BLOCKS) {
        for (int idx = threadIdx.x; idx < FDIM * HID; idx += 256) smem[idx] = W_enc[idx];
        __syncthreads();
        int row = b * 64 + (threadIdx.x >> 2);
        int c0 = (threadIdx.x & 3) * 16;
        if (row >= N_NODES) return;
        float acc[16];
#pragma unroll
        for (int j = 0; j < 16; ++j) acc[j] = b_enc[c0 + j];
        const float4* xr = (const float4*)(x + (size_t)row * FDIM);
        for (int k4 = 0; k4 < FDIM / 4; ++k4) {
            float4 xv = xr[k4];
            const float* wr = smem + (k4 * 4) * HID + c0;
#pragma unroll
            for (int j = 0; j < 16; ++j) acc[j] = fmaf(xv.x, wr[j], acc[j]);
#pragma unroll
            for (int j = 0; j < 16; ++j) acc[j] = fmaf(xv.y, wr[HID + j], acc[j]);
#pragma unroll
            for (int j = 0; j < 16; ++j) acc[j] = fmaf(xv.z, wr[2 * HID + j], acc[j]);
#pragma unroll
            for (int j = 0; j < 16; ++j) acc[j] = fmaf(xv.w, wr[3 * HID + j], acc[j]);
        }
        float* hr = h + (size_t)row * HID + c0;
#pragma unroll
        for (int j = 0; j < 16; ++j) hr[j] = acc[j];
    } else if (b < CONV_BLOCKS + MH_BLOCKS) {
        int i = (b - CONV_BLOCKS) * 256 + threadIdx.x;
        int2 v = ((const int2*)mh)[i];
        uint u0 = __float_as_uint((float)v.x) >> 16;
        uint u1 = __float_as_uint((float)v.y) >> 16;
        mhp[i] = u0 | (u1 << 16);
    } else if (b < CONV_BLOCKS + MH_BLOCKS + HLL_BLOCKS) {
        int i = (b - CONV_BLOCKS - MH_BLOCKS) * 256 + threadIdx.x;
        int4 v = ((const int4*)hll)[i];
        hp[i] = (uint)v.x | ((uint)v.y << 8) | ((uint)v.z << 16) | ((uint)v.w << 24);
    } else {
        int hb = b - CONV_BLOCKS - MH_BLOCKS - HLL_BLOCKS;
        int* hsh = (int*)smem;
        for (int i = threadIdx.x; i < NBUCK; i += 256) hsh[i] = 0;
        __syncthreads();
        int e0 = hb * EDGES_PER_HIST;
        for (int i = threadIdx.x; i < EDGES_PER_HIST; i += 256)
            atomicAdd(&hsh[dst[e0 + i] >> BSHIFT], 1);
        __syncthreads();
        for (int i = threadIdx.x; i < NBUCK; i += 256)
            hist2d[hb * NBUCK + i] = hsh[i];
    }
}

// reduce per-block hists -> bktcnt, exclusive scan -> gbase/gcur
__global__ void k_bktscan(const int* __restrict__ hist2d, int* __restrict__ bktcnt,
                          int* __restrict__ gbase, int* __restrict__ gcur,
                          int* __restrict__ offsets) {
    __shared__ int s[256];
    int t = threadIdx.x;
    int v = 0;
    if (t < NBUCK)
        for (int k = 0; k < HIST_BLOCKS; ++k) v += hist2d[k * NBUCK + t];
    s[t] = v;
    __syncthreads();
    for (int off = 1; off < 256; off <<= 1) {
        int u = (t >= off) ? s[t - off] : 0;
        __syncthreads();
        s[t] += u;
        __syncthreads();
    }
    if (t < NBUCK) {
        int ex = s[t] - v;
        bktcnt[t] = v; gbase[t] = ex; gcur[t] = ex;
    }
    if (t == 0) offsets[N_NODES] = N_EDGES + N_NODES;
}

// ---------------- pass A: block-local multisplit scatter ----------------

__global__ void __launch_bounds__(256) k_scatter(const int* __restrict__ src,
                          const int* __restrict__ dst,
                          int* __restrict__ gcur, uint* __restrict__ ebuf) {
    __shared__ uint ecache[EDGES_PER_BLK];
    __shared__ int cnt[NBUCK];
    __shared__ int cur[NBUCK];
    int t = threadIdx.x;
    for (int i = t; i < NBUCK; i += 256) cnt[i] = 0;
    __syncthreads();
    int e0 = blockIdx.x * EDGES_PER_BLK;
    for (int i = t; i < EDGES_PER_BLK; i += 256) {
        int d = dst[e0 + i];
        int s = src[e0 + i];
        ecache[i] = ((uint)s << 16) | (uint)d;   // both < 65536
        atomicAdd(&cnt[d >> BSHIFT], 1);
    }
    __syncthreads();
    for (int b = t; b < NBUCK; b += 256)
        cur[b] = atomicAdd(&gcur[b], cnt[b]);
    __syncthreads();
    for (int i = t; i < EDGES_PER_BLK; i += 256) {
        uint en = ecache[i];
        uint d = en & 0xFFFFu;
        int p = atomicAdd(&cur[d >> BSHIFT], 1);
        ebuf[p] = ((en >> 16) << BSHIFT) | (d & (BNODES - 1));
    }
}

// ---------------- pass B: build CSR slice (u16) in LDS; emit offsets/dis ----------------

__global__ void __launch_bounds__(256) k_csr(const uint* __restrict__ ebuf,
                      const int* __restrict__ gbase, const int* __restrict__ bktcnt,
                      int* __restrict__ offsets, float* __restrict__ dis,
                      ushort* __restrict__ csr) {
    __shared__ int lcur[BNODES];
    __shared__ int ssum[256];
    __shared__ uint slice[SLICE_CAP];
    int b = blockIdx.x;
    int lo = b << BSHIFT;
    int nbkt = min(BNODES, N_NODES - lo);
    int ebase = gbase[b];
    int ecnt = bktcnt[b];
    int t = threadIdx.x;
    lcur[t] = 0;
    __syncthreads();
    for (int i = t; i < ecnt; i += 256)
        atomicAdd(&lcur[ebuf[ebase + i] & (BNODES - 1)], 1);
    __syncthreads();
    int a0 = lcur[t];
    ssum[t] = a0;
    __syncthreads();
    for (int off = 1; off < 256; off <<= 1) {
        int u = (t >= off) ? ssum[t - off] : 0;
        __syncthreads();
        ssum[t] += u;
        __syncthreads();
    }
    int pre = ssum[t] - a0;
    if (t < nbkt) {
        int st = pre + t;
        slice[st] = (uint)(lo + t);       // self-loop first
        lcur[t] = st + 1;
        offsets[lo + t] = ebase + lo + st;
        dis[lo + t] = rsqrtf((float)(a0 + 1));
    }
    __syncthreads();
    for (int i = t; i < ecnt; i += 256) {
        uint en = ebuf[ebase + i];
        int p = atomicAdd(&lcur[en & (BNODES - 1)], 1);
        slice[p] = en >> BSHIFT;
    }
    __syncthreads();
    int slen = ecnt + nbkt;
    int gb = ebase + lo;
    for (int i = t; i < slen; i += 256) csr[gb + i] = (ushort)slice[i];
}

// ================= D1: mh0 | hll0 | conv0 =================

__global__ void __launch_bounds__(256) k_hopA(const int* __restrict__ offsets,
                    const ushort* __restrict__ csr,
                    const uint* __restrict__ mh_in, uint* __restrict__ mh_out_p,
                    const uint* __restrict__ hll_in, uint* __restrict__ hll_out_p,
                    float* __restrict__ cards,
                    const float* __restrict__ h, const float* __restrict__ W,
                    const float* __restrict__ dis, ushort* __restrict__ hWs) {
    __shared__ float Ws[HID * HID];
    int blk = blockIdx.x;
    if (blk < MH_BLOCKS) {
        int node = blk * 4 + (threadIdx.x >> 6);
        mh_body(node, threadIdx.x & 63, offsets, csr, mh_in, mh_out_p, nullptr);
    } else if (blk < MH_BLOCKS + HLL_BLOCKS) {
        int node = (blk - MH_BLOCKS) * 16 + (threadIdx.x >> 4);
        hll_body(node, threadIdx.x & 15, offsets, csr, hll_in, hll_out_p, nullptr, cards, 0);
    } else {
        for (int i = threadIdx.x; i < HID * HID; i += 256) Ws[i] = W[i];
        __syncthreads();
        int row = (blk - MH_BLOCKS - HLL_BLOCKS) * 64 + (threadIdx.x >> 2);
        if (row >= N_NODES) return;
        convmm_body(row, (threadIdx.x & 3) * 16, h, Ws, dis, hWs);
    }
}

// ================= D2: mh1 | agg0 | hll1 =================

__global__ void __launch_bounds__(256) k_hopB(const int* __restrict__ offsets,
                    const ushort* __restrict__ csr,
                    const uint* __restrict__ mh_in, float* __restrict__ mh_out_f,
                    const ushort* __restrict__ hWs, const float* __restrict__ b0,
                    float* __restrict__ h_cur,
                    const uint* __restrict__ hll_in, float* __restrict__ hll_out_f,
                    float* __restrict__ cards, const float* __restrict__ dis) {
    int blk = blockIdx.x;
    if (blk < MH_BLOCKS) {
        int node = blk * 4 + (threadIdx.x >> 6);
        mh_body(node, threadIdx.x & 63, offsets, csr, mh_in, nullptr, mh_out_f);
    } else if (blk < 2 * MH_BLOCKS) {
        int node = (blk - MH_BLOCKS) * 4 + (threadIdx.x >> 6);
        agg_body(node, threadIdx.x & 63, offsets, csr, hWs, dis, b0, h_cur, h_cur);
    } else {
        int node = (blk - 2 * MH_BLOCKS) * 16 + (threadIdx.x >> 4);
        hll_body(node, threadIdx.x & 15, offsets, csr, hll_in, nullptr, hll_out_f, cards, 1);
    }
}

// ================= D3: conv1 =================

__global__ void __launch_bounds__(256) k_conv(const float* __restrict__ h,
                         const float* __restrict__ W, const float* __restrict__ dis,
                         ushort* __restrict__ hWs) {
    __shared__ float Ws[HID * HID];
    for (int i = threadIdx.x; i < HID * HID; i += 256) Ws[i] = W[i];
    __syncthreads();
    int row = blockIdx.x * 64 + (threadIdx.x >> 2);
    if (row >= N_NODES) return;
    convmm_body(row, (threadIdx.x & 3) * 16, h, Ws, dis, hWs);
}

// ================= D4: agg1 -> out_h =================

__global__ void __launch_bounds__(256) k_agg(const int* __restrict__ offsets,
                      const ushort* __restrict__ csr, const ushort* __restrict__ hWs,
                      const float* __restrict__ dis, const float* __restrict__ b,
                      const float* __restrict__ h_in, float* __restrict__ h_out) {
    int node = blockIdx.x * 4 + (threadIdx.x >> 6);
    agg_body(node, threadIdx.x & 63, offsets, csr, hWs, dis, b, h_in, h_out);
}

// ---------------- driver ----------------

static inline char* align256(char* p) {
    return (char*)(((uintptr_t)p + 255) & ~(uintptr_t)255);
}

extern "C" void kernel_launch(void* const* d_in, const int* in_sizes, int n_in,
                              void* d_out, int out_size, void* d_ws, size_t ws_size,
                              hipStream_t stream) {
    const float* x       = (const float*)d_in[0];
    const int*   ei      = (const int*)d_in[1];
    const int*   mh0     = (const int*)d_in[2];
    const int*   hll0    = (const int*)d_in[3];
    const float* W_enc   = (const float*)d_in[4];
    const float* b_enc   = (const float*)d_in[5];
    const float* W_convs = (const float*)d_in[6];
    const float* b_convs = (const float*)d_in[7];

    float* out       = (float*)d_out;
    float* out_h     = out;
    float* out_cards = out + (size_t)N_NODES * HID;
    float* out_mh    = out_cards + (size_t)N_NODES * 2;
    float* out_hll   = out_mh + (size_t)N_NODES * NPERM;

    char* w = (char*)d_ws;
    int*   hist2d  = (int*)w;   w = align256(w + (size_t)HIST_BLOCKS * NBUCK * 4);
    int*   bktcnt  = (int*)w;   w = align256(w + (size_t)NBUCK * 4);
    int*   gbase   = (int*)w;   w = align256(w + (size_t)NBUCK * 4);
    int*   gcur    = (int*)w;   w = align256(w + (size_t)NBUCK * 4);
    int*   offsets = (int*)w;   w = align256(w + (size_t)(N_NODES + 1) * 4);
    float* dis     = (float*)w; w = align256(w + (size_t)N_NODES * 4);
    ushort* csr    = (ushort*)w; w = align256(w + (size_t)(N_EDGES + N_NODES) * 2);
    uint*  mhp0    = (uint*)w;  w = align256(w + (size_t)N_NODES * 64 * 4);
    uint*  mhA     = (uint*)w;  w = align256(w + (size_t)N_NODES * 64 * 4);
    uint*  hp0     = (uint*)w;  w = align256(w + (size_t)N_NODES * 16 * 4);
    uint*  hllA    = (uint*)w;  w = align256(w + (size_t)N_NODES * 16 * 4);
    float* h_cur   = (float*)w; w = align256(w + (size_t)N_NODES * HID * 4);
    ushort* hWs    = (ushort*)w; w = align256(w + (size_t)N_NODES * HID * 2);
    uint*  ebuf    = mhA;  // build-phase only; mhA first written after k_csr consumed ebuf

    const int* src = ei;
    const int* dst = ei + N_EDGES;

    k_prep<<<CONV_BLOCKS + MH_BLOCKS + HLL_BLOCKS + HIST_BLOCKS, 256, 0, stream>>>(
        x, W_enc, b_enc, h_cur, mh0, mhp0, hll0, hp0, dst, hist2d);
    k_bktscan<<<1, 256, 0, stream>>>(hist2d, bktcnt, gbase, gcur, offsets);
    k_scatter<<<SCAT_BLOCKS, 256, 0, stream>>>(src, dst, gcur, ebuf);
    k_csr<<<NBUCK, 256, 0, stream>>>(ebuf, gbase, bktcnt, offsets, dis, csr);

    // D1: mh0 | hll0 | conv0
    k_hopA<<<MH_BLOCKS + HLL_BLOCKS + CONV_BLOCKS, 256, 0, stream>>>(
        offsets, csr, mhp0, mhA, hp0, hllA, out_cards, h_cur, W_convs, dis, hWs);
    // D2: mh1 | agg0 | hll1
    k_hopB<<<2 * MH_BLOCKS + HLL_BLOCKS, 256, 0, stream>>>(
        offsets, csr, mhA, out_mh, hWs, b_convs, h_cur, hllA, out_hll, out_cards, dis);
    // D3: conv1
    k_conv<<<CONV_BLOCKS, 256, 0, stream>>>(h_cur, W_convs + HID * HID, dis, hWs);
    // D4: agg1 -> out_h
    k_agg<<<MH_BLOCKS, 256, 0, stream>>>(offsets, csr, hWs, dis, b_convs + HID, h_cur, out_h);
}

// Round 10
// 211.040 us; speedup vs baseline: 1.8030x; 1.0215x over previous
//
#include <hip/hip_runtime.h>
#include <hip/hip_bf16.h>

typedef unsigned int uint;
typedef unsigned short ushort;

#define N_NODES 50000
#define N_EDGES 800000
#define FDIM 128
#define HID 64
#define NPERM 128
#define HLLM 64
#define DUMMY 50000                // identity row index

#define BSHIFT 8
#define BNODES 256                 // nodes per bucket
#define NBUCK 196                  // ceil(50000/256)
#define SCAT_BLOCKS 256
#define EDGES_PER_BLK 3125         // 800000/256 exactly
#define HIST_BLOCKS 64
#define EDGES_PER_HIST 12500       // 800000/64 exactly
#define MH_BLOCKS 12500            // 4 nodes/block
#define HLL_BLOCKS 3125            // 16 nodes/block
#define SLICE_CAP 8448             // ecnt + 8*256 padding headroom
#define CONV_BLOCKS 782            // ceil(50000/64)

__device__ __forceinline__ uint pk_min_u16(uint a, uint b) {
    uint d;
    asm("v_pk_min_u16 %0, %1, %2" : "=v"(d) : "v"(a), "v"(b));
    return d;
}

// ================= gather bodies (padded CSR: no tails, no clamps) =================

__device__ __forceinline__ void mh_body(int node, uint l, const int2* __restrict__ off2,
                                        const ushort* __restrict__ csr,
                                        const uint* __restrict__ mh_in,
                                        uint* __restrict__ out_p, float* __restrict__ out_f) {
    int2 se = off2[node];
    uint mnA = 0xFFFFFFFFu, mnB = 0xFFFFFFFFu, mnC = 0xFFFFFFFFu, mnD = 0xFFFFFFFFu;
    for (int p = se.x; p < se.y; p += 8) {
        uint4 c4 = *(const uint4*)(csr + p);
        uint j0 = c4.x & 0xFFFFu, j1 = c4.x >> 16;
        uint j2 = c4.y & 0xFFFFu, j3 = c4.y >> 16;
        uint j4 = c4.z & 0xFFFFu, j5 = c4.z >> 16;
        uint j6 = c4.w & 0xFFFFu, j7 = c4.w >> 16;
        uint a0 = mh_in[j0 * 64u + l];
        uint a1 = mh_in[j1 * 64u + l];
        uint a2 = mh_in[j2 * 64u + l];
        uint a3 = mh_in[j3 * 64u + l];
        uint a4 = mh_in[j4 * 64u + l];
        uint a5 = mh_in[j5 * 64u + l];
        uint a6 = mh_in[j6 * 64u + l];
        uint a7 = mh_in[j7 * 64u + l];
        mnA = pk_min_u16(mnA, a0); mnB = pk_min_u16(mnB, a1);
        mnC = pk_min_u16(mnC, a2); mnD = pk_min_u16(mnD, a3);
        mnA = pk_min_u16(mnA, a4); mnB = pk_min_u16(mnB, a5);
        mnC = pk_min_u16(mnC, a6); mnD = pk_min_u16(mnD, a7);
    }
    mnA = pk_min_u16(pk_min_u16(mnA, mnB), pk_min_u16(mnC, mnD));
    uint mn0 = mnA & 0xFFFFu, mn1 = mnA >> 16;
    if (out_p) {
        out_p[(size_t)node * 64 + l] = mn0 | (mn1 << 16);
    } else {
        float2 w;
        w.x = __uint_as_float(mn0 << 16);
        w.y = __uint_as_float(mn1 << 16);
        *(float2*)(out_f + (size_t)node * NPERM + 2 * l) = w;
    }
}

__device__ __forceinline__ void hll_body(int node, uint q, const int2* __restrict__ off2,
                                         const ushort* __restrict__ csr,
                                         const uint* __restrict__ hll_in,
                                         uint* __restrict__ out_p, float* __restrict__ out_f,
                                         float* __restrict__ cards, int kcol) {
    int2 se = off2[node];
    uint m0 = 0, m1 = 0, m2 = 0, m3 = 0;
#define HLL_ACC(vv) do { uint _v = (vv); \
        m0 = max(m0, _v & 0xFFu); m1 = max(m1, (_v >> 8) & 0xFFu); \
        m2 = max(m2, (_v >> 16) & 0xFFu); m3 = max(m3, _v >> 24); } while (0)
    for (int p = se.x; p < se.y; p += 8) {
        uint4 c4 = *(const uint4*)(csr + p);
        uint j0 = c4.x & 0xFFFFu, j1 = c4.x >> 16;
        uint j2 = c4.y & 0xFFFFu, j3 = c4.y >> 16;
        uint j4 = c4.z & 0xFFFFu, j5 = c4.z >> 16;
        uint j6 = c4.w & 0xFFFFu, j7 = c4.w >> 16;
        uint a0 = hll_in[j0 * 16u + q];
        uint a1 = hll_in[j1 * 16u + q];
        uint a2 = hll_in[j2 * 16u + q];
        uint a3 = hll_in[j3 * 16u + q];
        uint a4 = hll_in[j4 * 16u + q];
        uint a5 = hll_in[j5 * 16u + q];
        uint a6 = hll_in[j6 * 16u + q];
        uint a7 = hll_in[j7 * 16u + q];
        HLL_ACC(a0); HLL_ACC(a1); HLL_ACC(a2); HLL_ACC(a3);
        HLL_ACC(a4); HLL_ACC(a5); HLL_ACC(a6); HLL_ACC(a7);
    }
#undef HLL_ACC
    if (out_p) out_p[(size_t)node * 16 + q] = m0 | (m1 << 8) | (m2 << 16) | (m3 << 24);
    if (out_f) {
        float4 w = {(float)m0, (float)m1, (float)m2, (float)m3};
        *(float4*)(out_f + (size_t)node * HLLM + 4 * q) = w;
    }
    float v = exp2f(-(float)m0) + exp2f(-(float)m1) + exp2f(-(float)m2) + exp2f(-(float)m3);
    v += __shfl_xor(v, 1); v += __shfl_xor(v, 2);
    v += __shfl_xor(v, 4); v += __shfl_xor(v, 8);
    if (q == 0) {
        const float alphamm = (float)(0.7213 / (1.0 + 1.079 / 64.0) * 64.0 * 64.0);
        cards[(size_t)node * 2 + kcol] = alphamm / v;
    }
}

__device__ __forceinline__ void agg_body(int node, uint c, const int2* __restrict__ off2,
                                         const ushort* __restrict__ csr,
                                         const ushort* __restrict__ hWs,
                                         const float* __restrict__ dis,
                                         const float* __restrict__ b,
                                         const float* __restrict__ h_in,
                                         float* __restrict__ h_out) {
    int2 se = off2[node];
    float acc0 = 0.f, acc1 = 0.f;
    for (int p = se.x; p < se.y; p += 8) {
        uint4 c4 = *(const uint4*)(csr + p);
        uint j0 = c4.x & 0xFFFFu, j1 = c4.x >> 16;
        uint j2 = c4.y & 0xFFFFu, j3 = c4.y >> 16;
        uint j4 = c4.z & 0xFFFFu, j5 = c4.z >> 16;
        uint j6 = c4.w & 0xFFFFu, j7 = c4.w >> 16;
        uint a0 = hWs[j0 * 64u + c];
        uint a1 = hWs[j1 * 64u + c];
        uint a2 = hWs[j2 * 64u + c];
        uint a3 = hWs[j3 * 64u + c];
        uint a4 = hWs[j4 * 64u + c];
        uint a5 = hWs[j5 * 64u + c];
        uint a6 = hWs[j6 * 64u + c];
        uint a7 = hWs[j7 * 64u + c];
        acc0 += __uint_as_float(a0 << 16) + __uint_as_float(a1 << 16)
              + __uint_as_float(a2 << 16) + __uint_as_float(a3 << 16);
        acc1 += __uint_as_float(a4 << 16) + __uint_as_float(a5 << 16)
              + __uint_as_float(a6 << 16) + __uint_as_float(a7 << 16);
    }
    float acc = acc0 + acc1;
    h_out[(size_t)node * HID + c] = h_in[(size_t)node * HID + c] + b[c] + dis[node] * acc;
}

__device__ __forceinline__ void convmm_body(int row, int c0, const float* __restrict__ h,
                                            const float* __restrict__ Ws,
                                            const float* __restrict__ dis,
                                            ushort* __restrict__ hWs) {
    float acc[16] = {0.f, 0.f, 0.f, 0.f, 0.f, 0.f, 0.f, 0.f,
                     0.f, 0.f, 0.f, 0.f, 0.f, 0.f, 0.f, 0.f};
    const float4* hr = (const float4*)(h + (size_t)row * HID);
    for (int k4 = 0; k4 < HID / 4; ++k4) {
        float4 hv = hr[k4];
        const float* wr = Ws + (k4 * 4) * HID + c0;
#pragma unroll
        for (int j = 0; j < 16; ++j) acc[j] = fmaf(hv.x, wr[j], acc[j]);
#pragma unroll
        for (int j = 0; j < 16; ++j) acc[j] = fmaf(hv.y, wr[HID + j], acc[j]);
#pragma unroll
        for (int j = 0; j < 16; ++j) acc[j] = fmaf(hv.z, wr[2 * HID + j], acc[j]);
#pragma unroll
        for (int j = 0; j < 16; ++j) acc[j] = fmaf(hv.w, wr[3 * HID + j], acc[j]);
    }
    float d = dis[row];
    ushort* o = hWs + (size_t)row * HID + c0;
#pragma unroll
    for (int j = 0; j < 16; ++j) {
        __hip_bfloat16 t = __float2bfloat16(d * acc[j]);
        o[j] = *(ushort*)&t;
    }
}

// ================= prep: encoder | pack mh | pack hll | hist | dummy init =================

__global__ void __launch_bounds__(256) k_prep(const float* __restrict__ x,
                       const float* __restrict__ W_enc, const float* __restrict__ b_enc,
                       float* __restrict__ h,
                       const int* __restrict__ mh, uint* __restrict__ mhp, uint* __restrict__ mhA,
                       const int* __restrict__ hll, uint* __restrict__ hp, uint* __restrict__ hllA,
                       const int* __restrict__ dst, int* __restrict__ hist2d) {
    __shared__ float smem[FDIM * HID];
    int b = blockIdx.x;
    if (b < CONV_BLOCKS) {
        for (int idx = threadIdx.x; idx < FDIM * HID; idx += 256) smem[idx] = W_enc[idx];
        __syncthreads();
        int row = b * 64 + (threadIdx.x >> 2);
        int c0 = (threadIdx.x & 3) * 16;
        if (row >= N_NODES) return;
        float acc[16];
#pragma unroll
        for (int j = 0; j < 16; ++j) acc[j] = b_enc[c0 + j];
        const float4* xr = (const float4*)(x + (size_t)row * FDIM);
        for (int k4 = 0; k4 < FDIM / 4; ++k4) {
            float4 xv = xr[k4];
            const float* wr = smem + (k4 * 4) * HID + c0;
#pragma unroll
            for (int j = 0; j < 16; ++j) acc[j] = fmaf(xv.x, wr[j], acc[j]);
#pragma unroll
            for (int j = 0; j < 16; ++j) acc[j] = fmaf(xv.y, wr[HID + j], acc[j]);
#pragma unroll
            for (int j = 0; j < 16; ++j) acc[j] = fmaf(xv.z, wr[2 * HID + j], acc[j]);
#pragma unroll
            for (int j = 0; j < 16; ++j) acc[j] = fmaf(xv.w, wr[3 * HID + j], acc[j]);
        }
        float* hr = h + (size_t)row * HID + c0;
#pragma unroll
        for (int j = 0; j < 16; ++j) hr[j] = acc[j];
    } else if (b < CONV_BLOCKS + MH_BLOCKS) {
        int i = (b - CONV_BLOCKS) * 256 + threadIdx.x;
        int2 v = ((const int2*)mh)[i];
        uint u0 = __float_as_uint((float)v.x) >> 16;
        uint u1 = __float_as_uint((float)v.y) >> 16;
        mhp[i] = u0 | (u1 << 16);
    } else if (b < CONV_BLOCKS + MH_BLOCKS + HLL_BLOCKS) {
        int i = (b - CONV_BLOCKS - MH_BLOCKS) * 256 + threadIdx.x;
        int4 v = ((const int4*)hll)[i];
        hp[i] = (uint)v.x | ((uint)v.y << 8) | ((uint)v.z << 16) | ((uint)v.w << 24);
    } else if (b < CONV_BLOCKS + MH_BLOCKS + HLL_BLOCKS + HIST_BLOCKS) {
        int hb = b - CONV_BLOCKS - MH_BLOCKS - HLL_BLOCKS;
        int* hsh = (int*)smem;
        for (int i = threadIdx.x; i < NBUCK; i += 256) hsh[i] = 0;
        __syncthreads();
        int e0 = hb * EDGES_PER_HIST;
        for (int i = threadIdx.x; i < EDGES_PER_HIST; i += 256)
            atomicAdd(&hsh[dst[e0 + i] >> BSHIFT], 1);
        __syncthreads();
        for (int i = threadIdx.x; i < NBUCK; i += 256)
            hist2d[hb * NBUCK + i] = hsh[i];
    } else {
        // dummy identity rows (row DUMMY)
        int t = threadIdx.x;
        if (t < 64) {
            mhp[(size_t)DUMMY * 64 + t] = 0xFFFFFFFFu;
            mhA[(size_t)DUMMY * 64 + t] = 0xFFFFFFFFu;
        } else if (t < 80) {
            hp[(size_t)DUMMY * 16 + (t - 64)] = 0u;
        } else if (t < 96) {
            hllA[(size_t)DUMMY * 16 + (t - 80)] = 0u;
        }
    }
}

// reduce per-block hists -> bktcnt, scan -> gbase/gcur; reset padded cursor
__global__ void k_bktscan(const int* __restrict__ hist2d, int* __restrict__ bktcnt,
                          int* __restrict__ gbase, int* __restrict__ gcur,
                          int* __restrict__ pcur) {
    __shared__ int s[256];
    int t = threadIdx.x;
    int v = 0;
    if (t < NBUCK)
        for (int k = 0; k < HIST_BLOCKS; ++k) v += hist2d[k * NBUCK + t];
    s[t] = v;
    __syncthreads();
    for (int off = 1; off < 256; off <<= 1) {
        int u = (t >= off) ? s[t - off] : 0;
        __syncthreads();
        s[t] += u;
        __syncthreads();
    }
    if (t < NBUCK) {
        int ex = s[t] - v;
        bktcnt[t] = v; gbase[t] = ex; gcur[t] = ex;
    }
    if (t == 0) pcur[0] = 0;
}

// ---------------- pass A: block-local multisplit scatter ----------------

__global__ void __launch_bounds__(256) k_scatter(const int* __restrict__ src,
                          const int* __restrict__ dst,
                          int* __restrict__ gcur, uint* __restrict__ ebuf) {
    __shared__ uint ecache[EDGES_PER_BLK];
    __shared__ int cnt[NBUCK];
    __shared__ int cur[NBUCK];
    int t = threadIdx.x;
    for (int i = t; i < NBUCK; i += 256) cnt[i] = 0;
    __syncthreads();
    int e0 = blockIdx.x * EDGES_PER_BLK;
    for (int i = t; i < EDGES_PER_BLK; i += 256) {
        int d = dst[e0 + i];
        int s = src[e0 + i];
        ecache[i] = ((uint)s << 16) | (uint)d;   // both < 65536
        atomicAdd(&cnt[d >> BSHIFT], 1);
    }
    __syncthreads();
    for (int b = t; b < NBUCK; b += 256)
        cur[b] = atomicAdd(&gcur[b], cnt[b]);
    __syncthreads();
    for (int i = t; i < EDGES_PER_BLK; i += 256) {
        uint en = ecache[i];
        uint d = en & 0xFFFFu;
        int p = atomicAdd(&cur[d >> BSHIFT], 1);
        ebuf[p] = ((en >> 16) << BSHIFT) | (d & (BNODES - 1));
    }
}

// ---------------- pass B: padded CSR slices in LDS; emit off2/dis ----------------

__global__ void __launch_bounds__(256) k_csr(const uint* __restrict__ ebuf,
                      const int* __restrict__ gbase, const int* __restrict__ bktcnt,
                      int* __restrict__ pcur, int2* __restrict__ off2,
                      float* __restrict__ dis, ushort* __restrict__ csr) {
    __shared__ int lcur[BNODES];
    __shared__ int ssum[256];
    __shared__ uint slice[SLICE_CAP];
    __shared__ int sbase;
    int b = blockIdx.x;
    int lo = b << BSHIFT;
    int nbkt = min(BNODES, N_NODES - lo);
    int ebase = gbase[b];
    int ecnt = bktcnt[b];
    int t = threadIdx.x;
    lcur[t] = 0;
    __syncthreads();
    for (int i = t; i < ecnt; i += 256)
        atomicAdd(&lcur[ebuf[ebase + i] & (BNODES - 1)], 1);
    __syncthreads();
    int a0 = lcur[t];                      // in-degree (excl self)
    int plen = (t < nbkt) ? ((a0 + 8) & ~7) : 0;   // padded length incl self
    ssum[t] = plen;
    __syncthreads();
    for (int off = 1; off < 256; off <<= 1) {
        int u = (t >= off) ? ssum[t - off] : 0;
        __syncthreads();
        ssum[t] += u;
        __syncthreads();
    }
    int ppre = ssum[t] - plen;
    if (t == 255) sbase = atomicAdd(pcur, ssum[255]);
    __syncthreads();
    int base = sbase;
    if (t < nbkt) {
        slice[ppre] = (uint)(lo + t);      // self-loop first
        lcur[t] = ppre + 1;
        off2[lo + t] = make_int2(base + ppre, base + ppre + plen);
        dis[lo + t] = rsqrtf((float)(a0 + 1));
    }
    __syncthreads();
    for (int i = t; i < ecnt; i += 256) {
        uint en = ebuf[ebase + i];
        int p = atomicAdd(&lcur[en & (BNODES - 1)], 1);
        slice[p] = en >> BSHIFT;
    }
    __syncthreads();
    if (t < nbkt)
        for (int i = lcur[t]; i < ppre + plen; ++i) slice[i] = DUMMY;
    __syncthreads();
    int total = ssum[255];
    for (int i = t; i < total; i += 256) csr[base + i] = (ushort)slice[i];
}

// ================= D1: mh0 | hll0 | conv0 =================

__global__ void __launch_bounds__(256) k_hopA(const int2* __restrict__ off2,
                    const ushort* __restrict__ csr,
                    const uint* __restrict__ mh_in, uint* __restrict__ mh_out_p,
                    const uint* __restrict__ hll_in, uint* __restrict__ hll_out_p,
                    float* __restrict__ cards,
                    const float* __restrict__ h, const float* __restrict__ W,
                    const float* __restrict__ dis, ushort* __restrict__ hWs) {
    __shared__ float Ws[HID * HID];
    int blk = blockIdx.x;
    if (blk < MH_BLOCKS) {
        int node = blk * 4 + (threadIdx.x >> 6);
        mh_body(node, threadIdx.x & 63, off2, csr, mh_in, mh_out_p, nullptr);
    } else if (blk < MH_BLOCKS + HLL_BLOCKS) {
        int node = (blk - MH_BLOCKS) * 16 + (threadIdx.x >> 4);
        hll_body(node, threadIdx.x & 15, off2, csr, hll_in, hll_out_p, nullptr, cards, 0);
    } else {
        for (int i = threadIdx.x; i < HID * HID; i += 256) Ws[i] = W[i];
        __syncthreads();
        int row = (blk - MH_BLOCKS - HLL_BLOCKS) * 64 + (threadIdx.x >> 2);
        int c0 = (threadIdx.x & 3) * 16;
        if (row > N_NODES) return;
        if (row == N_NODES) {           // dummy zero row
            ushort* o = hWs + (size_t)row * HID + c0;
#pragma unroll
            for (int j = 0; j < 16; ++j) o[j] = 0;
            return;
        }
        convmm_body(row, c0, h, Ws, dis, hWs);
    }
}

// ================= D2: mh1 | agg0 | hll1 =================

__global__ void __launch_bounds__(256) k_hopB(const int2* __restrict__ off2,
                    const ushort* __restrict__ csr,
                    const uint* __restrict__ mh_in, float* __restrict__ mh_out_f,
                    const ushort* __restrict__ hWs, const float* __restrict__ b0,
                    float* __restrict__ h_cur,
                    const uint* __restrict__ hll_in, float* __restrict__ hll_out_f,
                    float* __restrict__ cards, const float* __restrict__ dis) {
    int blk = blockIdx.x;
    if (blk < MH_BLOCKS) {
        int node = blk * 4 + (threadIdx.x >> 6);
        mh_body(node, threadIdx.x & 63, off2, csr, mh_in, nullptr, mh_out_f);
    } else if (blk < 2 * MH_BLOCKS) {
        int node = (blk - MH_BLOCKS) * 4 + (threadIdx.x >> 6);
        agg_body(node, threadIdx.x & 63, off2, csr, hWs, dis, b0, h_cur, h_cur);
    } else {
        int node = (blk - 2 * MH_BLOCKS) * 16 + (threadIdx.x >> 4);
        hll_body(node, threadIdx.x & 15, off2, csr, hll_in, nullptr, hll_out_f, cards, 1);
    }
}

// ================= D3: conv1 =================

__global__ void __launch_bounds__(256) k_conv(const float* __restrict__ h,
                         const float* __restrict__ W, const float* __restrict__ dis,
                         ushort* __restrict__ hWs) {
    __shared__ float Ws[HID * HID];
    for (int i = threadIdx.x; i < HID * HID; i += 256) Ws[i] = W[i];
    __syncthreads();
    int row = blockIdx.x * 64 + (threadIdx.x >> 2);
    int c0 = (threadIdx.x & 3) * 16;
    if (row > N_NODES) return;
    if (row == N_NODES) {
        ushort* o = hWs + (size_t)row * HID + c0;
#pragma unroll
        for (int j = 0; j < 16; ++j) o[j] = 0;
        return;
    }
    convmm_body(row, c0, h, Ws, dis, hWs);
}

// ================= D4: agg1 -> out_h =================

__global__ void __launch_bounds__(256) k_agg(const int2* __restrict__ off2,
                      const ushort* __restrict__ csr, const ushort* __restrict__ hWs,
                      const float* __restrict__ dis, const float* __restrict__ b,
                      const float* __restrict__ h_in, float* __restrict__ h_out) {
    int node = blockIdx.x * 4 + (threadIdx.x >> 6);
    agg_body(node, threadIdx.x & 63, off2, csr, hWs, dis, b, h_in, h_out);
}

// ---------------- driver ----------------

static inline char* align256(char* p) {
    return (char*)(((uintptr_t)p + 255) & ~(uintptr_t)255);
}

extern "C" void kernel_launch(void* const* d_in, const int* in_sizes, int n_in,
                              void* d_out, int out_size, void* d_ws, size_t ws_size,
                              hipStream_t stream) {
    const float* x       = (const float*)d_in[0];
    const int*   ei      = (const int*)d_in[1];
    const int*   mh0     = (const int*)d_in[2];
    const int*   hll0    = (const int*)d_in[3];
    const float* W_enc   = (const float*)d_in[4];
    const float* b_enc   = (const float*)d_in[5];
    const float* W_convs = (const float*)d_in[6];
    const float* b_convs = (const float*)d_in[7];

    float* out       = (float*)d_out;
    float* out_h     = out;
    float* out_cards = out + (size_t)N_NODES * HID;
    float* out_mh    = out_cards + (size_t)N_NODES * 2;
    float* out_hll   = out_mh + (size_t)N_NODES * NPERM;

    char* w = (char*)d_ws;
    int*   hist2d  = (int*)w;   w = align256(w + (size_t)HIST_BLOCKS * NBUCK * 4);
    int*   bktcnt  = (int*)w;   w = align256(w + (size_t)NBUCK * 4);
    int*   gbase   = (int*)w;   w = align256(w + (size_t)NBUCK * 4);
    int*   gcur    = (int*)w;   w = align256(w + (size_t)NBUCK * 4);
    int*   pcur    = (int*)w;   w = align256(w + 4);
    int2*  off2    = (int2*)w;  w = align256(w + (size_t)N_NODES * 8);
    float* dis     = (float*)w; w = align256(w + (size_t)N_NODES * 4);
    ushort* csr    = (ushort*)w; w = align256(w + (size_t)(N_EDGES + 8 * N_NODES) * 2);
    uint*  mhp0    = (uint*)w;  w = align256(w + (size_t)(N_NODES + 1) * 64 * 4);
    uint*  mhA     = (uint*)w;  w = align256(w + (size_t)(N_NODES + 1) * 64 * 4);
    uint*  hp0     = (uint*)w;  w = align256(w + (size_t)(N_NODES + 1) * 16 * 4);
    uint*  hllA    = (uint*)w;  w = align256(w + (size_t)(N_NODES + 1) * 16 * 4);
    float* h_cur   = (float*)w; w = align256(w + (size_t)N_NODES * HID * 4);
    ushort* hWs    = (ushort*)w; w = align256(w + (size_t)(N_NODES + 1) * HID * 2);
    uint*  ebuf    = mhA;  // build-phase alias; dummy row (offset 12.8MB) beyond ebuf extent (3.2MB)

    const int* src = ei;
    const int* dst = ei + N_EDGES;

    k_prep<<<CONV_BLOCKS + MH_BLOCKS + HLL_BLOCKS + HIST_BLOCKS + 1, 256, 0, stream>>>(
        x, W_enc, b_enc, h_cur, mh0, mhp0, mhA, hll0, hp0, hllA, dst, hist2d);
    k_bktscan<<<1, 256, 0, stream>>>(hist2d, bktcnt, gbase, gcur, pcur);
    k_scatter<<<SCAT_BLOCKS, 256, 0, stream>>>(src, dst, gcur, ebuf);
    k_csr<<<NBUCK, 256, 0, stream>>>(ebuf, gbase, bktcnt, pcur, off2, dis, csr);

    // D1: mh0 | hll0 | conv0
    k_hopA<<<MH_BLOCKS + HLL_BLOCKS + CONV_BLOCKS + 1, 256, 0, stream>>>(
        off2, csr, mhp0, mhA, hp0, hllA, out_cards, h_cur, W_convs, dis, hWs);
    // D2: mh1 | agg0 | hll1
    k_hopB<<<2 * MH_BLOCKS + HLL_BLOCKS, 256, 0, stream>>>(
        off2, csr, mhA, out_mh, hWs, b_convs, h_cur, hllA, out_hll, out_cards, dis);
    // D3: conv1
    k_conv<<<CONV_BLOCKS + 1, 256, 0, stream>>>(h_cur, W_convs + HID * HID, dis, hWs);
    // D4: agg1 -> out_h
    k_agg<<<MH_BLOCKS, 256, 0, stream>>>(off2, csr, hWs, dis, b_convs + HID, h_cur, out_h);
}

// Round 11
// 201.912 us; speedup vs baseline: 1.8845x; 1.0452x over previous
//
#include <hip/hip_runtime.h>
#include <hip/hip_bf16.h>

typedef unsigned int uint;
typedef unsigned short ushort;

#define N_NODES 50000
#define N_EDGES 800000
#define FDIM 128
#define HID 64
#define NPERM 128
#define HLLM 64
#define DUMMY 50000                // identity row index

#define BSHIFT 8
#define BNODES 256                 // nodes per bucket
#define NBUCK 196                  // ceil(50000/256)
#define CAPB 6144                  // fixed ebuf capacity/bucket (mean 4096, 32 sigma)
#define SCAT_BLOCKS 256
#define EDGES_PER_BLK 3125         // 800000/256 exactly
#define MH_BLOCKS 12500            // 4 nodes/block
#define HLL_BLOCKS 3125            // 16 nodes/block
#define SLICE_CAP 8448
#define CONV_BLOCKS 782            // ceil(50000/64)

__device__ __forceinline__ uint pk_min_u16(uint a, uint b) {
    uint d;
    asm("v_pk_min_u16 %0, %1, %2" : "=v"(d) : "v"(a), "v"(b));
    return d;
}

// ================= gather bodies (padded CSR: no tails, no clamps) =================

__device__ __forceinline__ void mh_body(int node, uint l, const int2* __restrict__ off2,
                                        const ushort* __restrict__ csr,
                                        const uint* __restrict__ mh_in,
                                        uint* __restrict__ out_p, float* __restrict__ out_f) {
    int2 se = off2[node];
    uint mnA = 0xFFFFFFFFu, mnB = 0xFFFFFFFFu, mnC = 0xFFFFFFFFu, mnD = 0xFFFFFFFFu;
    for (int p = se.x; p < se.y; p += 8) {
        uint4 c4 = *(const uint4*)(csr + p);
        uint j0 = c4.x & 0xFFFFu, j1 = c4.x >> 16;
        uint j2 = c4.y & 0xFFFFu, j3 = c4.y >> 16;
        uint j4 = c4.z & 0xFFFFu, j5 = c4.z >> 16;
        uint j6 = c4.w & 0xFFFFu, j7 = c4.w >> 16;
        uint a0 = mh_in[j0 * 64u + l];
        uint a1 = mh_in[j1 * 64u + l];
        uint a2 = mh_in[j2 * 64u + l];
        uint a3 = mh_in[j3 * 64u + l];
        uint a4 = mh_in[j4 * 64u + l];
        uint a5 = mh_in[j5 * 64u + l];
        uint a6 = mh_in[j6 * 64u + l];
        uint a7 = mh_in[j7 * 64u + l];
        mnA = pk_min_u16(mnA, a0); mnB = pk_min_u16(mnB, a1);
        mnC = pk_min_u16(mnC, a2); mnD = pk_min_u16(mnD, a3);
        mnA = pk_min_u16(mnA, a4); mnB = pk_min_u16(mnB, a5);
        mnC = pk_min_u16(mnC, a6); mnD = pk_min_u16(mnD, a7);
    }
    mnA = pk_min_u16(pk_min_u16(mnA, mnB), pk_min_u16(mnC, mnD));
    uint mn0 = mnA & 0xFFFFu, mn1 = mnA >> 16;
    if (out_p) {
        out_p[(size_t)node * 64 + l] = mn0 | (mn1 << 16);
    } else {
        float2 w;
        w.x = __uint_as_float(mn0 << 16);
        w.y = __uint_as_float(mn1 << 16);
        *(float2*)(out_f + (size_t)node * NPERM + 2 * l) = w;
    }
}

__device__ __forceinline__ void hll_body(int node, uint q, const int2* __restrict__ off2,
                                         const ushort* __restrict__ csr,
                                         const uint* __restrict__ hll_in,
                                         uint* __restrict__ out_p, float* __restrict__ out_f,
                                         float* __restrict__ cards, int kcol) {
    int2 se = off2[node];
    uint m0 = 0, m1 = 0, m2 = 0, m3 = 0;
#define HLL_ACC(vv) do { uint _v = (vv); \
        m0 = max(m0, _v & 0xFFu); m1 = max(m1, (_v >> 8) & 0xFFu); \
        m2 = max(m2, (_v >> 16) & 0xFFu); m3 = max(m3, _v >> 24); } while (0)
    for (int p = se.x; p < se.y; p += 8) {
        uint4 c4 = *(const uint4*)(csr + p);
        uint j0 = c4.x & 0xFFFFu, j1 = c4.x >> 16;
        uint j2 = c4.y & 0xFFFFu, j3 = c4.y >> 16;
        uint j4 = c4.z & 0xFFFFu, j5 = c4.z >> 16;
        uint j6 = c4.w & 0xFFFFu, j7 = c4.w >> 16;
        uint a0 = hll_in[j0 * 16u + q];
        uint a1 = hll_in[j1 * 16u + q];
        uint a2 = hll_in[j2 * 16u + q];
        uint a3 = hll_in[j3 * 16u + q];
        uint a4 = hll_in[j4 * 16u + q];
        uint a5 = hll_in[j5 * 16u + q];
        uint a6 = hll_in[j6 * 16u + q];
        uint a7 = hll_in[j7 * 16u + q];
        HLL_ACC(a0); HLL_ACC(a1); HLL_ACC(a2); HLL_ACC(a3);
        HLL_ACC(a4); HLL_ACC(a5); HLL_ACC(a6); HLL_ACC(a7);
    }
#undef HLL_ACC
    if (out_p) out_p[(size_t)node * 16 + q] = m0 | (m1 << 8) | (m2 << 16) | (m3 << 24);
    if (out_f) {
        float4 w = {(float)m0, (float)m1, (float)m2, (float)m3};
        *(float4*)(out_f + (size_t)node * HLLM + 4 * q) = w;
    }
    float v = exp2f(-(float)m0) + exp2f(-(float)m1) + exp2f(-(float)m2) + exp2f(-(float)m3);
    v += __shfl_xor(v, 1); v += __shfl_xor(v, 2);
    v += __shfl_xor(v, 4); v += __shfl_xor(v, 8);
    if (q == 0) {
        const float alphamm = (float)(0.7213 / (1.0 + 1.079 / 64.0) * 64.0 * 64.0);
        cards[(size_t)node * 2 + kcol] = alphamm / v;
    }
}

__device__ __forceinline__ void agg_body(int node, uint c, const int2* __restrict__ off2,
                                         const ushort* __restrict__ csr,
                                         const ushort* __restrict__ hWs,
                                         const float* __restrict__ dis,
                                         const float* __restrict__ b,
                                         const float* __restrict__ h_in,
                                         float* __restrict__ h_out) {
    int2 se = off2[node];
    float acc0 = 0.f, acc1 = 0.f;
    for (int p = se.x; p < se.y; p += 8) {
        uint4 c4 = *(const uint4*)(csr + p);
        uint j0 = c4.x & 0xFFFFu, j1 = c4.x >> 16;
        uint j2 = c4.y & 0xFFFFu, j3 = c4.y >> 16;
        uint j4 = c4.z & 0xFFFFu, j5 = c4.z >> 16;
        uint j6 = c4.w & 0xFFFFu, j7 = c4.w >> 16;
        uint a0 = hWs[j0 * 64u + c];
        uint a1 = hWs[j1 * 64u + c];
        uint a2 = hWs[j2 * 64u + c];
        uint a3 = hWs[j3 * 64u + c];
        uint a4 = hWs[j4 * 64u + c];
        uint a5 = hWs[j5 * 64u + c];
        uint a6 = hWs[j6 * 64u + c];
        uint a7 = hWs[j7 * 64u + c];
        acc0 += __uint_as_float(a0 << 16) + __uint_as_float(a1 << 16)
              + __uint_as_float(a2 << 16) + __uint_as_float(a3 << 16);
        acc1 += __uint_as_float(a4 << 16) + __uint_as_float(a5 << 16)
              + __uint_as_float(a6 << 16) + __uint_as_float(a7 << 16);
    }
    float acc = acc0 + acc1;
    h_out[(size_t)node * HID + c] = h_in[(size_t)node * HID + c] + b[c] + dis[node] * acc;
}

__device__ __forceinline__ void convmm_body(int row, int c0, const float* __restrict__ h,
                                            const float* __restrict__ Ws,
                                            const float* __restrict__ dis,
                                            ushort* __restrict__ hWs) {
    float acc[16] = {0.f, 0.f, 0.f, 0.f, 0.f, 0.f, 0.f, 0.f,
                     0.f, 0.f, 0.f, 0.f, 0.f, 0.f, 0.f, 0.f};
    const float4* hr = (const float4*)(h + (size_t)row * HID);
    for (int k4 = 0; k4 < HID / 4; ++k4) {
        float4 hv = hr[k4];
        const float* wr = Ws + (k4 * 4) * HID + c0;
#pragma unroll
        for (int j = 0; j < 16; ++j) acc[j] = fmaf(hv.x, wr[j], acc[j]);
#pragma unroll
        for (int j = 0; j < 16; ++j) acc[j] = fmaf(hv.y, wr[HID + j], acc[j]);
#pragma unroll
        for (int j = 0; j < 16; ++j) acc[j] = fmaf(hv.z, wr[2 * HID + j], acc[j]);
#pragma unroll
        for (int j = 0; j < 16; ++j) acc[j] = fmaf(hv.w, wr[3 * HID + j], acc[j]);
    }
    float d = dis[row];
    ushort* o = hWs + (size_t)row * HID + c0;
#pragma unroll
    for (int j = 0; j < 16; ++j) {
        __hip_bfloat16 t = __float2bfloat16(d * acc[j]);
        o[j] = *(ushort*)&t;
    }
}

// ================= pack: mh | hll | init (no LDS -> full occupancy) =================

__global__ void __launch_bounds__(256) k_pack(const int* __restrict__ mh, uint* __restrict__ mhp,
                       uint* __restrict__ mhA,
                       const int* __restrict__ hll, uint* __restrict__ hp,
                       uint* __restrict__ hllA,
                       int* __restrict__ gcur, int* __restrict__ pcur) {
    int b = blockIdx.x;
    if (b < MH_BLOCKS) {
        // minhash int32 -> top16(float32) u16 (monotone, err <= |v|/256)
        int i = b * 256 + threadIdx.x;
        int2 v = ((const int2*)mh)[i];
        uint u0 = __float_as_uint((float)v.x) >> 16;
        uint u1 = __float_as_uint((float)v.y) >> 16;
        mhp[i] = u0 | (u1 << 16);
    } else if (b < MH_BLOCKS + HLL_BLOCKS) {
        // hll int32 (<20; max-only keeps <256) -> u8 packed
        int i = (b - MH_BLOCKS) * 256 + threadIdx.x;
        int4 v = ((const int4*)hll)[i];
        hp[i] = (uint)v.x | ((uint)v.y << 8) | ((uint)v.z << 16) | ((uint)v.w << 24);
    } else {
        int t = threadIdx.x;
        if (t < NBUCK) gcur[t] = t * CAPB;          // fixed bucket bases
        if (t == 255) pcur[0] = 0;
        if (t < 64) {
            mhp[(size_t)DUMMY * 64 + t] = 0xFFFFFFFFu;
            mhA[(size_t)DUMMY * 64 + t] = 0xFFFFFFFFu;
        } else if (t < 80) {
            hp[(size_t)DUMMY * 16 + (t - 64)] = 0u;
        } else if (t < 96) {
            hllA[(size_t)DUMMY * 16 + (t - 80)] = 0u;
        }
    }
}

// ================= encoder: h = x @ W_enc + b =================

__global__ void __launch_bounds__(256) k_enc(const float* __restrict__ x,
                       const float* __restrict__ W_enc, const float* __restrict__ b_enc,
                       float* __restrict__ h) {
    __shared__ float smem[FDIM * HID];
    for (int idx = threadIdx.x; idx < FDIM * HID; idx += 256) smem[idx] = W_enc[idx];
    __syncthreads();
    int row = blockIdx.x * 64 + (threadIdx.x >> 2);
    int c0 = (threadIdx.x & 3) * 16;
    if (row >= N_NODES) return;
    float acc[16];
#pragma unroll
    for (int j = 0; j < 16; ++j) acc[j] = b_enc[c0 + j];
    const float4* xr = (const float4*)(x + (size_t)row * FDIM);
    for (int k4 = 0; k4 < FDIM / 4; ++k4) {
        float4 xv = xr[k4];
        const float* wr = smem + (k4 * 4) * HID + c0;
#pragma unroll
        for (int j = 0; j < 16; ++j) acc[j] = fmaf(xv.x, wr[j], acc[j]);
#pragma unroll
        for (int j = 0; j < 16; ++j) acc[j] = fmaf(xv.y, wr[HID + j], acc[j]);
#pragma unroll
        for (int j = 0; j < 16; ++j) acc[j] = fmaf(xv.z, wr[2 * HID + j], acc[j]);
#pragma unroll
        for (int j = 0; j < 16; ++j) acc[j] = fmaf(xv.w, wr[3 * HID + j], acc[j]);
    }
    float* hr = h + (size_t)row * HID + c0;
#pragma unroll
    for (int j = 0; j < 16; ++j) hr[j] = acc[j];
}

// ---------------- pass A: block-local multisplit scatter (fixed bucket bases) ----------------

__global__ void __launch_bounds__(256) k_scatter(const int* __restrict__ src,
                          const int* __restrict__ dst,
                          int* __restrict__ gcur, uint* __restrict__ ebuf) {
    __shared__ uint ecache[EDGES_PER_BLK];
    __shared__ int cnt[NBUCK];
    __shared__ int cur[NBUCK];
    int t = threadIdx.x;
    for (int i = t; i < NBUCK; i += 256) cnt[i] = 0;
    __syncthreads();
    int e0 = blockIdx.x * EDGES_PER_BLK;
    for (int i = t; i < EDGES_PER_BLK; i += 256) {
        int d = dst[e0 + i];
        int s = src[e0 + i];
        ecache[i] = ((uint)s << 16) | (uint)d;   // both < 65536
        atomicAdd(&cnt[d >> BSHIFT], 1);
    }
    __syncthreads();
    for (int b = t; b < NBUCK; b += 256)
        cur[b] = atomicAdd(&gcur[b], cnt[b]);
    __syncthreads();
    for (int i = t; i < EDGES_PER_BLK; i += 256) {
        uint en = ecache[i];
        uint d = en & 0xFFFFu;
        int p = atomicAdd(&cur[d >> BSHIFT], 1);
        ebuf[p] = ((en >> 16) << BSHIFT) | (d & (BNODES - 1));
    }
}

// ---------------- pass B: padded CSR slices in LDS; emit off2/dis ----------------

__global__ void __launch_bounds__(256) k_csr(const uint* __restrict__ ebuf,
                      const int* __restrict__ gcur, int* __restrict__ pcur,
                      int2* __restrict__ off2, float* __restrict__ dis,
                      ushort* __restrict__ csr) {
    __shared__ int lcur[BNODES];
    __shared__ int ssum[256];
    __shared__ uint slice[SLICE_CAP];
    __shared__ int sbase;
    int b = blockIdx.x;
    int lo = b << BSHIFT;
    int nbkt = min(BNODES, N_NODES - lo);
    int ebase = b * CAPB;
    int ecnt = gcur[b] - ebase;
    int t = threadIdx.x;
    lcur[t] = 0;
    __syncthreads();
    for (int i = t; i < ecnt; i += 256)
        atomicAdd(&lcur[ebuf[ebase + i] & (BNODES - 1)], 1);
    __syncthreads();
    int a0 = lcur[t];                      // in-degree (excl self)
    int plen = (t < nbkt) ? ((a0 + 8) & ~7) : 0;   // padded length incl self
    ssum[t] = plen;
    __syncthreads();
    for (int off = 1; off < 256; off <<= 1) {
        int u = (t >= off) ? ssum[t - off] : 0;
        __syncthreads();
        ssum[t] += u;
        __syncthreads();
    }
    int ppre = ssum[t] - plen;
    if (t == 255) sbase = atomicAdd(pcur, ssum[255]);
    __syncthreads();
    int base = sbase;
    if (t < nbkt) {
        slice[ppre] = (uint)(lo + t);      // self-loop first
        lcur[t] = ppre + 1;
        off2[lo + t] = make_int2(base + ppre, base + ppre + plen);
        dis[lo + t] = rsqrtf((float)(a0 + 1));
    }
    __syncthreads();
    for (int i = t; i < ecnt; i += 256) {
        uint en = ebuf[ebase + i];
        int p = atomicAdd(&lcur[en & (BNODES - 1)], 1);
        slice[p] = en >> BSHIFT;
    }
    __syncthreads();
    if (t < nbkt)
        for (int i = lcur[t]; i < ppre + plen; ++i) slice[i] = DUMMY;
    __syncthreads();
    int total = ssum[255];
    for (int i = t; i < total; i += 256) csr[base + i] = (ushort)slice[i];
}

// ================= D1: mh0 | hll0 | conv0 =================

__global__ void __launch_bounds__(256) k_hopA(const int2* __restrict__ off2,
                    const ushort* __restrict__ csr,
                    const uint* __restrict__ mh_in, uint* __restrict__ mh_out_p,
                    const uint* __restrict__ hll_in, uint* __restrict__ hll_out_p,
                    float* __restrict__ cards,
                    const float* __restrict__ h, const float* __restrict__ W,
                    const float* __restrict__ dis, ushort* __restrict__ hWs) {
    __shared__ float Ws[HID * HID];
    int blk = blockIdx.x;
    if (blk < MH_BLOCKS) {
        int node = blk * 4 + (threadIdx.x >> 6);
        mh_body(node, threadIdx.x & 63, off2, csr, mh_in, mh_out_p, nullptr);
    } else if (blk < MH_BLOCKS + HLL_BLOCKS) {
        int node = (blk - MH_BLOCKS) * 16 + (threadIdx.x >> 4);
        hll_body(node, threadIdx.x & 15, off2, csr, hll_in, hll_out_p, nullptr, cards, 0);
    } else {
        for (int i = threadIdx.x; i < HID * HID; i += 256) Ws[i] = W[i];
        __syncthreads();
        int row = (blk - MH_BLOCKS - HLL_BLOCKS) * 64 + (threadIdx.x >> 2);
        int c0 = (threadIdx.x & 3) * 16;
        if (row > N_NODES) return;
        if (row == N_NODES) {           // dummy zero row
            ushort* o = hWs + (size_t)row * HID + c0;
#pragma unroll
            for (int j = 0; j < 16; ++j) o[j] = 0;
            return;
        }
        convmm_body(row, c0, h, Ws, dis, hWs);
    }
}

// ================= D2: mh1 | agg0 | hll1 =================

__global__ void __launch_bounds__(256) k_hopB(const int2* __restrict__ off2,
                    const ushort* __restrict__ csr,
                    const uint* __restrict__ mh_in, float* __restrict__ mh_out_f,
                    const ushort* __restrict__ hWs, const float* __restrict__ b0,
                    float* __restrict__ h_cur,
                    const uint* __restrict__ hll_in, float* __restrict__ hll_out_f,
                    float* __restrict__ cards, const float* __restrict__ dis) {
    int blk = blockIdx.x;
    if (blk < MH_BLOCKS) {
        int node = blk * 4 + (threadIdx.x >> 6);
        mh_body(node, threadIdx.x & 63, off2, csr, mh_in, nullptr, mh_out_f);
    } else if (blk < 2 * MH_BLOCKS) {
        int node = (blk - MH_BLOCKS) * 4 + (threadIdx.x >> 6);
        agg_body(node, threadIdx.x & 63, off2, csr, hWs, dis, b0, h_cur, h_cur);
    } else {
        int node = (blk - 2 * MH_BLOCKS) * 16 + (threadIdx.x >> 4);
        hll_body(node, threadIdx.x & 15, off2, csr, hll_in, nullptr, hll_out_f, cards, 1);
    }
}

// ================= D3: conv1 =================

__global__ void __launch_bounds__(256) k_conv(const float* __restrict__ h,
                         const float* __restrict__ W, const float* __restrict__ dis,
                         ushort* __restrict__ hWs) {
    __shared__ float Ws[HID * HID];
    for (int i = threadIdx.x; i < HID * HID; i += 256) Ws[i] = W[i];
    __syncthreads();
    int row = blockIdx.x * 64 + (threadIdx.x >> 2);
    int c0 = (threadIdx.x & 3) * 16;
    if (row > N_NODES) return;
    if (row == N_NODES) {
        ushort* o = hWs + (size_t)row * HID + c0;
#pragma unroll
        for (int j = 0; j < 16; ++j) o[j] = 0;
        return;
    }
    convmm_body(row, c0, h, Ws, dis, hWs);
}

// ================= D4: agg1 -> out_h =================

__global__ void __launch_bounds__(256) k_agg(const int2* __restrict__ off2,
                      const ushort* __restrict__ csr, const ushort* __restrict__ hWs,
                      const float* __restrict__ dis, const float* __restrict__ b,
                      const float* __restrict__ h_in, float* __restrict__ h_out) {
    int node = blockIdx.x * 4 + (threadIdx.x >> 6);
    agg_body(node, threadIdx.x & 63, off2, csr, hWs, dis, b, h_in, h_out);
}

// ---------------- driver ----------------

static inline char* align256(char* p) {
    return (char*)(((uintptr_t)p + 255) & ~(uintptr_t)255);
}

extern "C" void kernel_launch(void* const* d_in, const int* in_sizes, int n_in,
                              void* d_out, int out_size, void* d_ws, size_t ws_size,
                              hipStream_t stream) {
    const float* x       = (const float*)d_in[0];
    const int*   ei      = (const int*)d_in[1];
    const int*   mh0     = (const int*)d_in[2];
    const int*   hll0    = (const int*)d_in[3];
    const float* W_enc   = (const float*)d_in[4];
    const float* b_enc   = (const float*)d_in[5];
    const float* W_convs = (const float*)d_in[6];
    const float* b_convs = (const float*)d_in[7];

    float* out       = (float*)d_out;
    float* out_h     = out;
    float* out_cards = out + (size_t)N_NODES * HID;
    float* out_mh    = out_cards + (size_t)N_NODES * 2;
    float* out_hll   = out_mh + (size_t)N_NODES * NPERM;

    char* w = (char*)d_ws;
    int*   gcur    = (int*)w;   w = align256(w + (size_t)NBUCK * 4);
    int*   pcur    = (int*)w;   w = align256(w + 4);
    int2*  off2    = (int2*)w;  w = align256(w + (size_t)N_NODES * 8);
    float* dis     = (float*)w; w = align256(w + (size_t)N_NODES * 4);
    ushort* csr    = (ushort*)w; w = align256(w + (size_t)(N_EDGES + 8 * N_NODES) * 2);
    uint*  mhp0    = (uint*)w;  w = align256(w + (size_t)(N_NODES + 1) * 64 * 4);
    uint*  mhA     = (uint*)w;  w = align256(w + (size_t)(N_NODES + 1) * 64 * 4);
    uint*  hp0     = (uint*)w;  w = align256(w + (size_t)(N_NODES + 1) * 16 * 4);
    uint*  hllA    = (uint*)w;  w = align256(w + (size_t)(N_NODES + 1) * 16 * 4);
    float* h_cur   = (float*)w; w = align256(w + (size_t)N_NODES * HID * 4);
    ushort* hWs    = (ushort*)w; w = align256(w + (size_t)(N_NODES + 1) * HID * 2);
    uint*  ebuf    = mhA;  // build-phase alias (196*6144 uints = 4.8MB < 12.8MB extent);
                           // dummy row at 12.8MB offset untouched by ebuf

    const int* src = ei;
    const int* dst = ei + N_EDGES;

    // front-end: pack (no LDS) -> scatter -> csr -> encoder
    k_pack<<<MH_BLOCKS + HLL_BLOCKS + 1, 256, 0, stream>>>(
        mh0, mhp0, mhA, hll0, hp0, hllA, gcur, pcur);
    k_scatter<<<SCAT_BLOCKS, 256, 0, stream>>>(src, dst, gcur, ebuf);
    k_csr<<<NBUCK, 256, 0, stream>>>(ebuf, gcur, pcur, off2, dis, csr);
    k_enc<<<CONV_BLOCKS, 256, 0, stream>>>(x, W_enc, b_enc, h_cur);

    // D1: mh0 | hll0 | conv0
    k_hopA<<<MH_BLOCKS + HLL_BLOCKS + CONV_BLOCKS + 1, 256, 0, stream>>>(
        off2, csr, mhp0, mhA, hp0, hllA, out_cards, h_cur, W_convs, dis, hWs);
    // D2: mh1 | agg0 | hll1
    k_hopB<<<2 * MH_BLOCKS + HLL_BLOCKS, 256, 0, stream>>>(
        off2, csr, mhA, out_mh, hWs, b_convs, h_cur, hllA, out_hll, out_cards, dis);
    // D3: conv1
    k_conv<<<CONV_BLOCKS + 1, 256, 0, stream>>>(h_cur, W_convs + HID * HID, dis, hWs);
    // D4: agg1 -> out_h
    k_agg<<<MH_BLOCKS, 256, 0, stream>>>(off2, csr, hWs, dis, b_convs + HID, h_cur, out_h);
}

// Round 12
// 184.768 us; speedup vs baseline: 2.0594x; 1.0928x over previous
//
#include <hip/hip_runtime.h>
#include <hip/hip_bf16.h>

typedef unsigned int uint;
typedef unsigned short ushort;

#define N_NODES 50000
#define N_EDGES 800000
#define FDIM 128
#define HID 64
#define NPERM 128
#define HLLM 64
#define DUMMY 50000                // identity row index

#define BSHIFT 8
#define BNODES 256                 // nodes per bucket
#define NBUCK 196                  // ceil(50000/256)
#define CAPB 6144                  // fixed ebuf capacity/bucket (mean 4096, 32 sigma)
#define SCAT_BLOCKS 256
#define EDGES_PER_BLK 3125         // 800000/256 exactly
#define MH_BLOCKS 12500            // 4 nodes/block
#define HLL_BLOCKS 3125            // 16 nodes/block
#define SLICE_CAP 8448
#define CONV_BLOCKS 782            // ceil(50000/64)

__device__ __forceinline__ uint pk_min_u16(uint a, uint b) {
    uint d;
    asm("v_pk_min_u16 %0, %1, %2" : "=v"(d) : "v"(a), "v"(b));
    return d;
}

// ================= gather bodies (padded CSR: no tails, no clamps) =================

__device__ __forceinline__ void mh_body(int node, uint l, const int2* __restrict__ off2,
                                        const ushort* __restrict__ csr,
                                        const uint* __restrict__ mh_in,
                                        uint* __restrict__ out_p, float* __restrict__ out_f) {
    int2 se = off2[node];
    uint mnA = 0xFFFFFFFFu, mnB = 0xFFFFFFFFu, mnC = 0xFFFFFFFFu, mnD = 0xFFFFFFFFu;
#pragma unroll 2
    for (int p = se.x; p < se.y; p += 8) {
        uint4 c4 = *(const uint4*)(csr + p);
        uint j0 = c4.x & 0xFFFFu, j1 = c4.x >> 16;
        uint j2 = c4.y & 0xFFFFu, j3 = c4.y >> 16;
        uint j4 = c4.z & 0xFFFFu, j5 = c4.z >> 16;
        uint j6 = c4.w & 0xFFFFu, j7 = c4.w >> 16;
        uint a0 = mh_in[j0 * 64u + l];
        uint a1 = mh_in[j1 * 64u + l];
        uint a2 = mh_in[j2 * 64u + l];
        uint a3 = mh_in[j3 * 64u + l];
        uint a4 = mh_in[j4 * 64u + l];
        uint a5 = mh_in[j5 * 64u + l];
        uint a6 = mh_in[j6 * 64u + l];
        uint a7 = mh_in[j7 * 64u + l];
        mnA = pk_min_u16(mnA, a0); mnB = pk_min_u16(mnB, a1);
        mnC = pk_min_u16(mnC, a2); mnD = pk_min_u16(mnD, a3);
        mnA = pk_min_u16(mnA, a4); mnB = pk_min_u16(mnB, a5);
        mnC = pk_min_u16(mnC, a6); mnD = pk_min_u16(mnD, a7);
    }
    mnA = pk_min_u16(pk_min_u16(mnA, mnB), pk_min_u16(mnC, mnD));
    uint mn0 = mnA & 0xFFFFu, mn1 = mnA >> 16;
    if (out_p) {
        out_p[(size_t)node * 64 + l] = mn0 | (mn1 << 16);
    } else {
        float2 w;
        w.x = __uint_as_float(mn0 << 16);
        w.y = __uint_as_float(mn1 << 16);
        *(float2*)(out_f + (size_t)node * NPERM + 2 * l) = w;
    }
}

__device__ __forceinline__ void hll_body(int node, uint q, const int2* __restrict__ off2,
                                         const ushort* __restrict__ csr,
                                         const uint* __restrict__ hll_in,
                                         uint* __restrict__ out_p, float* __restrict__ out_f,
                                         float* __restrict__ cards, int kcol) {
    int2 se = off2[node];
    uint m0 = 0, m1 = 0, m2 = 0, m3 = 0;
#define HLL_ACC(vv) do { uint _v = (vv); \
        m0 = max(m0, _v & 0xFFu); m1 = max(m1, (_v >> 8) & 0xFFu); \
        m2 = max(m2, (_v >> 16) & 0xFFu); m3 = max(m3, _v >> 24); } while (0)
#pragma unroll 2
    for (int p = se.x; p < se.y; p += 8) {
        uint4 c4 = *(const uint4*)(csr + p);
        uint j0 = c4.x & 0xFFFFu, j1 = c4.x >> 16;
        uint j2 = c4.y & 0xFFFFu, j3 = c4.y >> 16;
        uint j4 = c4.z & 0xFFFFu, j5 = c4.z >> 16;
        uint j6 = c4.w & 0xFFFFu, j7 = c4.w >> 16;
        uint a0 = hll_in[j0 * 16u + q];
        uint a1 = hll_in[j1 * 16u + q];
        uint a2 = hll_in[j2 * 16u + q];
        uint a3 = hll_in[j3 * 16u + q];
        uint a4 = hll_in[j4 * 16u + q];
        uint a5 = hll_in[j5 * 16u + q];
        uint a6 = hll_in[j6 * 16u + q];
        uint a7 = hll_in[j7 * 16u + q];
        HLL_ACC(a0); HLL_ACC(a1); HLL_ACC(a2); HLL_ACC(a3);
        HLL_ACC(a4); HLL_ACC(a5); HLL_ACC(a6); HLL_ACC(a7);
    }
#undef HLL_ACC
    if (out_p) out_p[(size_t)node * 16 + q] = m0 | (m1 << 8) | (m2 << 16) | (m3 << 24);
    if (out_f) {
        float4 w = {(float)m0, (float)m1, (float)m2, (float)m3};
        *(float4*)(out_f + (size_t)node * HLLM + 4 * q) = w;
    }
    float v = exp2f(-(float)m0) + exp2f(-(float)m1) + exp2f(-(float)m2) + exp2f(-(float)m3);
    v += __shfl_xor(v, 1); v += __shfl_xor(v, 2);
    v += __shfl_xor(v, 4); v += __shfl_xor(v, 8);
    if (q == 0) {
        const float alphamm = (float)(0.7213 / (1.0 + 1.079 / 64.0) * 64.0 * 64.0);
        cards[(size_t)node * 2 + kcol] = alphamm / v;
    }
}

__device__ __forceinline__ void agg_body(int node, uint c, const int2* __restrict__ off2,
                                         const ushort* __restrict__ csr,
                                         const ushort* __restrict__ hWs,
                                         const float* __restrict__ dis,
                                         const float* __restrict__ b,
                                         const float* __restrict__ h_in,
                                         float* __restrict__ h_out) {
    int2 se = off2[node];
    float acc0 = 0.f, acc1 = 0.f;
#pragma unroll 2
    for (int p = se.x; p < se.y; p += 8) {
        uint4 c4 = *(const uint4*)(csr + p);
        uint j0 = c4.x & 0xFFFFu, j1 = c4.x >> 16;
        uint j2 = c4.y & 0xFFFFu, j3 = c4.y >> 16;
        uint j4 = c4.z & 0xFFFFu, j5 = c4.z >> 16;
        uint j6 = c4.w & 0xFFFFu, j7 = c4.w >> 16;
        uint a0 = hWs[j0 * 64u + c];
        uint a1 = hWs[j1 * 64u + c];
        uint a2 = hWs[j2 * 64u + c];
        uint a3 = hWs[j3 * 64u + c];
        uint a4 = hWs[j4 * 64u + c];
        uint a5 = hWs[j5 * 64u + c];
        uint a6 = hWs[j6 * 64u + c];
        uint a7 = hWs[j7 * 64u + c];
        acc0 += __uint_as_float(a0 << 16) + __uint_as_float(a1 << 16)
              + __uint_as_float(a2 << 16) + __uint_as_float(a3 << 16);
        acc1 += __uint_as_float(a4 << 16) + __uint_as_float(a5 << 16)
              + __uint_as_float(a6 << 16) + __uint_as_float(a7 << 16);
    }
    float acc = acc0 + acc1;
    h_out[(size_t)node * HID + c] = h_in[(size_t)node * HID + c] + b[c] + dis[node] * acc;
}

__device__ __forceinline__ void convmm_body(int row, int c0, const float* __restrict__ h,
                                            const float* __restrict__ Ws,
                                            const float* __restrict__ dis,
                                            ushort* __restrict__ hWs) {
    float acc[16] = {0.f, 0.f, 0.f, 0.f, 0.f, 0.f, 0.f, 0.f,
                     0.f, 0.f, 0.f, 0.f, 0.f, 0.f, 0.f, 0.f};
    const float4* hr = (const float4*)(h + (size_t)row * HID);
    for (int k4 = 0; k4 < HID / 4; ++k4) {
        float4 hv = hr[k4];
        const float* wr = Ws + (k4 * 4) * HID + c0;
#pragma unroll
        for (int j = 0; j < 16; ++j) acc[j] = fmaf(hv.x, wr[j], acc[j]);
#pragma unroll
        for (int j = 0; j < 16; ++j) acc[j] = fmaf(hv.y, wr[HID + j], acc[j]);
#pragma unroll
        for (int j = 0; j < 16; ++j) acc[j] = fmaf(hv.z, wr[2 * HID + j], acc[j]);
#pragma unroll
        for (int j = 0; j < 16; ++j) acc[j] = fmaf(hv.w, wr[3 * HID + j], acc[j]);
    }
    float d = dis[row];
    ushort* o = hWs + (size_t)row * HID + c0;
#pragma unroll
    for (int j = 0; j < 16; ++j) {
        __hip_bfloat16 t = __float2bfloat16(d * acc[j]);
        o[j] = *(ushort*)&t;
    }
}

// ================= k_front: scatter | pack mh | pack hll | dummy init =================
// gcur pre-zeroed by memset; scatter adds fixed base b*CAPB in-kernel.

__global__ void __launch_bounds__(256) k_front(const int* __restrict__ src,
                       const int* __restrict__ dst, int* __restrict__ gcur,
                       uint* __restrict__ ebuf,
                       const int* __restrict__ mh, uint* __restrict__ mhp,
                       uint* __restrict__ mhA,
                       const int* __restrict__ hll, uint* __restrict__ hp,
                       uint* __restrict__ hllA) {
    __shared__ uint ecache[EDGES_PER_BLK];
    __shared__ int cnt[NBUCK];
    __shared__ int cur[NBUCK];
    int b = blockIdx.x;
    int t = threadIdx.x;
    if (b < SCAT_BLOCKS) {
        for (int i = t; i < NBUCK; i += 256) cnt[i] = 0;
        __syncthreads();
        int e0 = b * EDGES_PER_BLK;
        for (int i = t; i < EDGES_PER_BLK; i += 256) {
            int d = dst[e0 + i];
            int s = src[e0 + i];
            ecache[i] = ((uint)s << 16) | (uint)d;   // both < 65536
            atomicAdd(&cnt[d >> BSHIFT], 1);
        }
        __syncthreads();
        for (int bb = t; bb < NBUCK; bb += 256)
            cur[bb] = bb * CAPB + atomicAdd(&gcur[bb], cnt[bb]);
        __syncthreads();
        for (int i = t; i < EDGES_PER_BLK; i += 256) {
            uint en = ecache[i];
            uint d = en & 0xFFFFu;
            int p = atomicAdd(&cur[d >> BSHIFT], 1);
            ebuf[p] = ((en >> 16) << BSHIFT) | (d & (BNODES - 1));
        }
    } else if (b < SCAT_BLOCKS + MH_BLOCKS) {
        // minhash int32 -> top16(float32) u16 (monotone, err <= |v|/256)
        int i = (b - SCAT_BLOCKS) * 256 + t;
        int2 v = ((const int2*)mh)[i];
        uint u0 = __float_as_uint((float)v.x) >> 16;
        uint u1 = __float_as_uint((float)v.y) >> 16;
        mhp[i] = u0 | (u1 << 16);
    } else if (b < SCAT_BLOCKS + MH_BLOCKS + HLL_BLOCKS) {
        // hll int32 (<20; max-only keeps <256) -> u8 packed
        int i = (b - SCAT_BLOCKS - MH_BLOCKS) * 256 + t;
        int4 v = ((const int4*)hll)[i];
        hp[i] = (uint)v.x | ((uint)v.y << 8) | ((uint)v.z << 16) | ((uint)v.w << 24);
    } else {
        if (t < 64) {
            mhp[(size_t)DUMMY * 64 + t] = 0xFFFFFFFFu;
            mhA[(size_t)DUMMY * 64 + t] = 0xFFFFFFFFu;
        } else if (t < 80) {
            hp[(size_t)DUMMY * 16 + (t - 64)] = 0u;
        } else if (t < 96) {
            hllA[(size_t)DUMMY * 16 + (t - 80)] = 0u;
        }
    }
}

// ================= k_fat1: csr | encoder =================

__global__ void __launch_bounds__(256) k_fat1(const uint* __restrict__ ebuf,
                      const int* __restrict__ gcur, int* __restrict__ pcur,
                      int2* __restrict__ off2, float* __restrict__ dis,
                      ushort* __restrict__ csr,
                      const float* __restrict__ x, const float* __restrict__ W_enc,
                      const float* __restrict__ b_enc, float* __restrict__ h) {
    __shared__ uint smem[SLICE_CAP + BNODES + 256 + 1];   // ~35.8 KB
    int b = blockIdx.x;
    int t = threadIdx.x;
    if (b < NBUCK) {
        uint* slice = smem;
        int* lcur = (int*)(smem + SLICE_CAP);
        int* ssum = (int*)(smem + SLICE_CAP + BNODES);
        int* sbase = (int*)(smem + SLICE_CAP + BNODES + 256);
        int lo = b << BSHIFT;
        int nbkt = min(BNODES, N_NODES - lo);
        int ebase = b * CAPB;
        int ecnt = gcur[b];
        lcur[t] = 0;
        __syncthreads();
        for (int i = t; i < ecnt; i += 256)
            atomicAdd(&lcur[ebuf[ebase + i] & (BNODES - 1)], 1);
        __syncthreads();
        int a0 = lcur[t];                      // in-degree (excl self)
        int plen = (t < nbkt) ? ((a0 + 8) & ~7) : 0;   // padded length incl self
        ssum[t] = plen;
        __syncthreads();
        for (int off = 1; off < 256; off <<= 1) {
            int u = (t >= off) ? ssum[t - off] : 0;
            __syncthreads();
            ssum[t] += u;
            __syncthreads();
        }
        int ppre = ssum[t] - plen;
        if (t == 255) sbase[0] = atomicAdd(pcur, ssum[255]);
        __syncthreads();
        int base = sbase[0];
        if (t < nbkt) {
            slice[ppre] = (uint)(lo + t);      // self-loop first
            lcur[t] = ppre + 1;
            off2[lo + t] = make_int2(base + ppre, base + ppre + plen);
            dis[lo + t] = rsqrtf((float)(a0 + 1));
        }
        __syncthreads();
        for (int i = t; i < ecnt; i += 256) {
            uint en = ebuf[ebase + i];
            int p = atomicAdd(&lcur[en & (BNODES - 1)], 1);
            slice[p] = en >> BSHIFT;
        }
        __syncthreads();
        if (t < nbkt)
            for (int i = lcur[t]; i < ppre + plen; ++i) slice[i] = DUMMY;
        __syncthreads();
        int total = ssum[255];
        for (int i = t; i < total; i += 256) csr[base + i] = (ushort)slice[i];
    } else {
        float* Ws = (float*)smem;
        for (int idx = t; idx < FDIM * HID; idx += 256) Ws[idx] = W_enc[idx];
        __syncthreads();
        int row = (b - NBUCK) * 64 + (t >> 2);
        int c0 = (t & 3) * 16;
        if (row >= N_NODES) return;
        float acc[16];
#pragma unroll
        for (int j = 0; j < 16; ++j) acc[j] = b_enc[c0 + j];
        const float4* xr = (const float4*)(x + (size_t)row * FDIM);
        for (int k4 = 0; k4 < FDIM / 4; ++k4) {
            float4 xv = xr[k4];
            const float* wr = Ws + (k4 * 4) * HID + c0;
#pragma unroll
            for (int j = 0; j < 16; ++j) acc[j] = fmaf(xv.x, wr[j], acc[j]);
#pragma unroll
            for (int j = 0; j < 16; ++j) acc[j] = fmaf(xv.y, wr[HID + j], acc[j]);
#pragma unroll
            for (int j = 0; j < 16; ++j) acc[j] = fmaf(xv.z, wr[2 * HID + j], acc[j]);
#pragma unroll
            for (int j = 0; j < 16; ++j) acc[j] = fmaf(xv.w, wr[3 * HID + j], acc[j]);
        }
        float* hr = h + (size_t)row * HID + c0;
#pragma unroll
        for (int j = 0; j < 16; ++j) hr[j] = acc[j];
    }
}

// ================= D1: mh0 | hll0 | conv0 =================

__global__ void __launch_bounds__(256) k_hopA(const int2* __restrict__ off2,
                    const ushort* __restrict__ csr,
                    const uint* __restrict__ mh_in, uint* __restrict__ mh_out_p,
                    const uint* __restrict__ hll_in, uint* __restrict__ hll_out_p,
                    float* __restrict__ cards,
                    const float* __restrict__ h, const float* __restrict__ W,
                    const float* __restrict__ dis, ushort* __restrict__ hWs) {
    __shared__ float Ws[HID * HID];
    int blk = blockIdx.x;
    if (blk < MH_BLOCKS) {
        int node = blk * 4 + (threadIdx.x >> 6);
        mh_body(node, threadIdx.x & 63, off2, csr, mh_in, mh_out_p, nullptr);
    } else if (blk < MH_BLOCKS + HLL_BLOCKS) {
        int node = (blk - MH_BLOCKS) * 16 + (threadIdx.x >> 4);
        hll_body(node, threadIdx.x & 15, off2, csr, hll_in, hll_out_p, nullptr, cards, 0);
    } else {
        for (int i = threadIdx.x; i < HID * HID; i += 256) Ws[i] = W[i];
        __syncthreads();
        int row = (blk - MH_BLOCKS - HLL_BLOCKS) * 64 + (threadIdx.x >> 2);
        int c0 = (threadIdx.x & 3) * 16;
        if (row > N_NODES) return;
        if (row == N_NODES) {           // dummy zero row
            ushort* o = hWs + (size_t)row * HID + c0;
#pragma unroll
            for (int j = 0; j < 16; ++j) o[j] = 0;
            return;
        }
        convmm_body(row, c0, h, Ws, dis, hWs);
    }
}

// ================= D2: mh1 | agg0 | hll1 =================

__global__ void __launch_bounds__(256) k_hopB(const int2* __restrict__ off2,
                    const ushort* __restrict__ csr,
                    const uint* __restrict__ mh_in, float* __restrict__ mh_out_f,
                    const ushort* __restrict__ hWs, const float* __restrict__ b0,
                    float* __restrict__ h_cur,
                    const uint* __restrict__ hll_in, float* __restrict__ hll_out_f,
                    float* __restrict__ cards, const float* __restrict__ dis) {
    int blk = blockIdx.x;
    if (blk < MH_BLOCKS) {
        int node = blk * 4 + (threadIdx.x >> 6);
        mh_body(node, threadIdx.x & 63, off2, csr, mh_in, nullptr, mh_out_f);
    } else if (blk < 2 * MH_BLOCKS) {
        int node = (blk - MH_BLOCKS) * 4 + (threadIdx.x >> 6);
        agg_body(node, threadIdx.x & 63, off2, csr, hWs, dis, b0, h_cur, h_cur);
    } else {
        int node = (blk - 2 * MH_BLOCKS) * 16 + (threadIdx.x >> 4);
        hll_body(node, threadIdx.x & 15, off2, csr, hll_in, nullptr, hll_out_f, cards, 1);
    }
}

// ================= D3: conv1 =================

__global__ void __launch_bounds__(256) k_conv(const float* __restrict__ h,
                         const float* __restrict__ W, const float* __restrict__ dis,
                         ushort* __restrict__ hWs) {
    __shared__ float Ws[HID * HID];
    for (int i = threadIdx.x; i < HID * HID; i += 256) Ws[i] = W[i];
    __syncthreads();
    int row = blockIdx.x * 64 + (threadIdx.x >> 2);
    int c0 = (threadIdx.x & 3) * 16;
    if (row > N_NODES) return;
    if (row == N_NODES) {
        ushort* o = hWs + (size_t)row * HID + c0;
#pragma unroll
        for (int j = 0; j < 16; ++j) o[j] = 0;
        return;
    }
    convmm_body(row, c0, h, Ws, dis, hWs);
}

// ================= D4: agg1 -> out_h =================

__global__ void __launch_bounds__(256) k_agg(const int2* __restrict__ off2,
                      const ushort* __restrict__ csr, const ushort* __restrict__ hWs,
                      const float* __restrict__ dis, const float* __restrict__ b,
                      const float* __restrict__ h_in, float* __restrict__ h_out) {
    int node = blockIdx.x * 4 + (threadIdx.x >> 6);
    agg_body(node, threadIdx.x & 63, off2, csr, hWs, dis, b, h_in, h_out);
}

// ---------------- driver ----------------

static inline char* align256(char* p) {
    return (char*)(((uintptr_t)p + 255) & ~(uintptr_t)255);
}

extern "C" void kernel_launch(void* const* d_in, const int* in_sizes, int n_in,
                              void* d_out, int out_size, void* d_ws, size_t ws_size,
                              hipStream_t stream) {
    const float* x       = (const float*)d_in[0];
    const int*   ei      = (const int*)d_in[1];
    const int*   mh0     = (const int*)d_in[2];
    const int*   hll0    = (const int*)d_in[3];
    const float* W_enc   = (const float*)d_in[4];
    const float* b_enc   = (const float*)d_in[5];
    const float* W_convs = (const float*)d_in[6];
    const float* b_convs = (const float*)d_in[7];

    float* out       = (float*)d_out;
    float* out_h     = out;
    float* out_cards = out + (size_t)N_NODES * HID;
    float* out_mh    = out_cards + (size_t)N_NODES * 2;
    float* out_hll   = out_mh + (size_t)N_NODES * NPERM;

    char* w = (char*)d_ws;
    int*   gcur    = (int*)w;   w += (size_t)NBUCK * 4;
    int*   pcur    = (int*)w;   w = align256(w + 4);
    int2*  off2    = (int2*)w;  w = align256(w + (size_t)N_NODES * 8);
    float* dis     = (float*)w; w = align256(w + (size_t)N_NODES * 4);
    ushort* csr    = (ushort*)w; w = align256(w + (size_t)(N_EDGES + 8 * N_NODES) * 2);
    uint*  mhp0    = (uint*)w;  w = align256(w + (size_t)(N_NODES + 1) * 64 * 4);
    uint*  mhA     = (uint*)w;  w = align256(w + (size_t)(N_NODES + 1) * 64 * 4);
    uint*  hp0     = (uint*)w;  w = align256(w + (size_t)(N_NODES + 1) * 16 * 4);
    uint*  hllA    = (uint*)w;  w = align256(w + (size_t)(N_NODES + 1) * 16 * 4);
    float* h_cur   = (float*)w; w = align256(w + (size_t)N_NODES * HID * 4);
    ushort* hWs    = (ushort*)w; w = align256(w + (size_t)(N_NODES + 1) * HID * 2);
    uint*  ebuf    = mhA;  // build-phase alias (196*6144 uints = 4.8MB < 12.8MB extent);
                           // dummy row at 12.8MB offset untouched by ebuf

    const int* src = ei;
    const int* dst = ei + N_EDGES;

    // zero gcur (+pcur, adjacent) -> fixed bucket bases added in-kernel
    hipMemsetAsync(gcur, 0, (size_t)(NBUCK + 1) * 4, stream);
    // F1: scatter | pack mh | pack hll | dummy init
    k_front<<<SCAT_BLOCKS + MH_BLOCKS + HLL_BLOCKS + 1, 256, 0, stream>>>(
        src, dst, gcur, ebuf, mh0, mhp0, mhA, hll0, hp0, hllA);
    // F2: csr | encoder
    k_fat1<<<NBUCK + CONV_BLOCKS, 256, 0, stream>>>(
        ebuf, gcur, pcur, off2, dis, csr, x, W_enc, b_enc, h_cur);

    // D1: mh0 | hll0 | conv0
    k_hopA<<<MH_BLOCKS + HLL_BLOCKS + CONV_BLOCKS + 1, 256, 0, stream>>>(
        off2, csr, mhp0, mhA, hp0, hllA, out_cards, h_cur, W_convs, dis, hWs);
    // D2: mh1 | agg0 | hll1
    k_hopB<<<2 * MH_BLOCKS + HLL_BLOCKS, 256, 0, stream>>>(
        off2, csr, mhA, out_mh, hWs, b_convs, h_cur, hllA, out_hll, out_cards, dis);
    // D3: conv1
    k_conv<<<CONV_BLOCKS + 1, 256, 0, stream>>>(h_cur, W_convs + HID * HID, dis, hWs);
    // D4: agg1 -> out_h
    k_agg<<<MH_BLOCKS, 256, 0, stream>>>(off2, csr, hWs, dis, b_convs + HID, h_cur, out_h);
}

// Round 13
// 176.788 us; speedup vs baseline: 2.1523x; 1.0451x over previous
//
#include <hip/hip_runtime.h>
#include <hip/hip_bf16.h>

typedef unsigned int uint;
typedef unsigned short ushort;

#define N_NODES 50000
#define N_EDGES 800000
#define FDIM 128
#define HID 64
#define NPERM 128
#define HLLM 64
#define DUMMY 50000                // identity row index

#define BSHIFT 8
#define BNODES 256                 // nodes per bucket
#define NBUCK 196                  // ceil(50000/256)
#define CAPB 6144                  // fixed ebuf capacity/bucket (mean 4096, 32 sigma)
#define SCAT_BLOCKS 256
#define EDGES_PER_BLK 3125         // 800000/256 exactly
#define MH2_BLOCKS 6250            // 8 nodes/block (2 per wave)
#define AGG2_BLOCKS 6250           // 8 nodes/block (2 per wave)
#define HLL_BLOCKS 3125            // 16 nodes/block
#define SLICE_CAP 8448
#define CONV_BLOCKS 782            // ceil(50000/64)

__device__ __forceinline__ uint pk_min_u16(uint a, uint b) {
    uint d;
    asm("v_pk_min_u16 %0, %1, %2" : "=v"(d) : "v"(a), "v"(b));
    return d;
}

// ========== mh: 2 nodes/wave, lanes 0-31 node A / 32-63 node B, uint2/lane ==========
// lane covers packed-uints {2*c2, 2*c2+1} of its node's row (32 lanes x 8B = 256B row)

__device__ __forceinline__ void mh_body(int node, uint c2, const int2* __restrict__ off2,
                                        const ushort* __restrict__ csr,
                                        const uint* __restrict__ mh_in,
                                        uint* __restrict__ out_p, float* __restrict__ out_f) {
    int2 se = off2[node];
    uint mnA = 0xFFFFFFFFu, mnB = 0xFFFFFFFFu, mnC = 0xFFFFFFFFu, mnD = 0xFFFFFFFFu;
    for (int p = se.x; p < se.y; p += 8) {
        uint4 c4 = *(const uint4*)(csr + p);
        uint j0 = c4.x & 0xFFFFu, j1 = c4.x >> 16;
        uint j2 = c4.y & 0xFFFFu, j3 = c4.y >> 16;
        uint j4 = c4.z & 0xFFFFu, j5 = c4.z >> 16;
        uint j6 = c4.w & 0xFFFFu, j7 = c4.w >> 16;
        uint2 a0 = *(const uint2*)(mh_in + j0 * 64u + 2u * c2);
        uint2 a1 = *(const uint2*)(mh_in + j1 * 64u + 2u * c2);
        uint2 a2 = *(const uint2*)(mh_in + j2 * 64u + 2u * c2);
        uint2 a3 = *(const uint2*)(mh_in + j3 * 64u + 2u * c2);
        uint2 a4 = *(const uint2*)(mh_in + j4 * 64u + 2u * c2);
        uint2 a5 = *(const uint2*)(mh_in + j5 * 64u + 2u * c2);
        uint2 a6 = *(const uint2*)(mh_in + j6 * 64u + 2u * c2);
        uint2 a7 = *(const uint2*)(mh_in + j7 * 64u + 2u * c2);
        mnA = pk_min_u16(mnA, a0.x); mnB = pk_min_u16(mnB, a0.y);
        mnC = pk_min_u16(mnC, a1.x); mnD = pk_min_u16(mnD, a1.y);
        mnA = pk_min_u16(mnA, a2.x); mnB = pk_min_u16(mnB, a2.y);
        mnC = pk_min_u16(mnC, a3.x); mnD = pk_min_u16(mnD, a3.y);
        mnA = pk_min_u16(mnA, a4.x); mnB = pk_min_u16(mnB, a4.y);
        mnC = pk_min_u16(mnC, a5.x); mnD = pk_min_u16(mnD, a5.y);
        mnA = pk_min_u16(mnA, a6.x); mnB = pk_min_u16(mnB, a6.y);
        mnC = pk_min_u16(mnC, a7.x); mnD = pk_min_u16(mnD, a7.y);
    }
    uint m0 = pk_min_u16(mnA, mnC);     // packed perms {4c2, 4c2+1}
    uint m1 = pk_min_u16(mnB, mnD);     // packed perms {4c2+2, 4c2+3}
    if (out_p) {
        uint2 w = {m0, m1};
        *(uint2*)(out_p + (size_t)node * 64 + 2u * c2) = w;
    } else {
        float4 w;
        w.x = __uint_as_float((m0 & 0xFFFFu) << 16);
        w.y = __uint_as_float(m0 & 0xFFFF0000u);
        w.z = __uint_as_float((m1 & 0xFFFFu) << 16);
        w.w = __uint_as_float(m1 & 0xFFFF0000u);
        *(float4*)(out_f + (size_t)node * NPERM + 4u * c2) = w;
    }
}

// ========== hll: 16 lanes/node (4 chains/wave already) ==========

__device__ __forceinline__ void hll_body(int node, uint q, const int2* __restrict__ off2,
                                         const ushort* __restrict__ csr,
                                         const uint* __restrict__ hll_in,
                                         uint* __restrict__ out_p, float* __restrict__ out_f,
                                         float* __restrict__ cards, int kcol) {
    int2 se = off2[node];
    uint m0 = 0, m1 = 0, m2 = 0, m3 = 0;
#define HLL_ACC(vv) do { uint _v = (vv); \
        m0 = max(m0, _v & 0xFFu); m1 = max(m1, (_v >> 8) & 0xFFu); \
        m2 = max(m2, (_v >> 16) & 0xFFu); m3 = max(m3, _v >> 24); } while (0)
#pragma unroll 2
    for (int p = se.x; p < se.y; p += 8) {
        uint4 c4 = *(const uint4*)(csr + p);
        uint j0 = c4.x & 0xFFFFu, j1 = c4.x >> 16;
        uint j2 = c4.y & 0xFFFFu, j3 = c4.y >> 16;
        uint j4 = c4.z & 0xFFFFu, j5 = c4.z >> 16;
        uint j6 = c4.w & 0xFFFFu, j7 = c4.w >> 16;
        uint a0 = hll_in[j0 * 16u + q];
        uint a1 = hll_in[j1 * 16u + q];
        uint a2 = hll_in[j2 * 16u + q];
        uint a3 = hll_in[j3 * 16u + q];
        uint a4 = hll_in[j4 * 16u + q];
        uint a5 = hll_in[j5 * 16u + q];
        uint a6 = hll_in[j6 * 16u + q];
        uint a7 = hll_in[j7 * 16u + q];
        HLL_ACC(a0); HLL_ACC(a1); HLL_ACC(a2); HLL_ACC(a3);
        HLL_ACC(a4); HLL_ACC(a5); HLL_ACC(a6); HLL_ACC(a7);
    }
#undef HLL_ACC
    if (out_p) out_p[(size_t)node * 16 + q] = m0 | (m1 << 8) | (m2 << 16) | (m3 << 24);
    if (out_f) {
        float4 w = {(float)m0, (float)m1, (float)m2, (float)m3};
        *(float4*)(out_f + (size_t)node * HLLM + 4 * q) = w;
    }
    float v = exp2f(-(float)m0) + exp2f(-(float)m1) + exp2f(-(float)m2) + exp2f(-(float)m3);
    v += __shfl_xor(v, 1); v += __shfl_xor(v, 2);
    v += __shfl_xor(v, 4); v += __shfl_xor(v, 8);
    if (q == 0) {
        const float alphamm = (float)(0.7213 / (1.0 + 1.079 / 64.0) * 64.0 * 64.0);
        cards[(size_t)node * 2 + kcol] = alphamm / v;
    }
}

// ========== agg: 2 nodes/wave, uint/lane (2 channels), 32 lanes x 4B = 128B row ==========

__device__ __forceinline__ void agg_body(int node, uint c2, const int2* __restrict__ off2,
                                         const ushort* __restrict__ csr,
                                         const uint* __restrict__ hWs32,
                                         const float* __restrict__ dis,
                                         const float* __restrict__ b,
                                         const float* __restrict__ h_in,
                                         float* __restrict__ h_out) {
    int2 se = off2[node];
    float ax0 = 0.f, ay0 = 0.f, ax1 = 0.f, ay1 = 0.f;
    for (int p = se.x; p < se.y; p += 8) {
        uint4 c4 = *(const uint4*)(csr + p);
        uint j0 = c4.x & 0xFFFFu, j1 = c4.x >> 16;
        uint j2 = c4.y & 0xFFFFu, j3 = c4.y >> 16;
        uint j4 = c4.z & 0xFFFFu, j5 = c4.z >> 16;
        uint j6 = c4.w & 0xFFFFu, j7 = c4.w >> 16;
        uint a0 = hWs32[j0 * 32u + c2];
        uint a1 = hWs32[j1 * 32u + c2];
        uint a2 = hWs32[j2 * 32u + c2];
        uint a3 = hWs32[j3 * 32u + c2];
        uint a4 = hWs32[j4 * 32u + c2];
        uint a5 = hWs32[j5 * 32u + c2];
        uint a6 = hWs32[j6 * 32u + c2];
        uint a7 = hWs32[j7 * 32u + c2];
        ax0 += __uint_as_float(a0 << 16) + __uint_as_float(a1 << 16)
             + __uint_as_float(a2 << 16) + __uint_as_float(a3 << 16);
        ay0 += __uint_as_float(a0 & 0xFFFF0000u) + __uint_as_float(a1 & 0xFFFF0000u)
             + __uint_as_float(a2 & 0xFFFF0000u) + __uint_as_float(a3 & 0xFFFF0000u);
        ax1 += __uint_as_float(a4 << 16) + __uint_as_float(a5 << 16)
             + __uint_as_float(a6 << 16) + __uint_as_float(a7 << 16);
        ay1 += __uint_as_float(a4 & 0xFFFF0000u) + __uint_as_float(a5 & 0xFFFF0000u)
             + __uint_as_float(a6 & 0xFFFF0000u) + __uint_as_float(a7 & 0xFFFF0000u);
    }
    float ax = ax0 + ax1, ay = ay0 + ay1;
    uint ch = 2u * c2;
    size_t idx = (size_t)node * HID + ch;
    float2 hi = *(const float2*)(h_in + idx);
    float2 bb = *(const float2*)(b + ch);
    float d = dis[node];
    float2 o;
    o.x = hi.x + bb.x + d * ax;
    o.y = hi.y + bb.y + d * ay;
    *(float2*)(h_out + idx) = o;
}

__device__ __forceinline__ void convmm_body(int row, int c0, const float* __restrict__ h,
                                            const float* __restrict__ Ws,
                                            const float* __restrict__ dis,
                                            ushort* __restrict__ hWs) {
    float acc[16] = {0.f, 0.f, 0.f, 0.f, 0.f, 0.f, 0.f, 0.f,
                     0.f, 0.f, 0.f, 0.f, 0.f, 0.f, 0.f, 0.f};
    const float4* hr = (const float4*)(h + (size_t)row * HID);
    for (int k4 = 0; k4 < HID / 4; ++k4) {
        float4 hv = hr[k4];
        const float* wr = Ws + (k4 * 4) * HID + c0;
#pragma unroll
        for (int j = 0; j < 16; ++j) acc[j] = fmaf(hv.x, wr[j], acc[j]);
#pragma unroll
        for (int j = 0; j < 16; ++j) acc[j] = fmaf(hv.y, wr[HID + j], acc[j]);
#pragma unroll
        for (int j = 0; j < 16; ++j) acc[j] = fmaf(hv.z, wr[2 * HID + j], acc[j]);
#pragma unroll
        for (int j = 0; j < 16; ++j) acc[j] = fmaf(hv.w, wr[3 * HID + j], acc[j]);
    }
    float d = dis[row];
    ushort* o = hWs + (size_t)row * HID + c0;
#pragma unroll
    for (int j = 0; j < 16; ++j) {
        __hip_bfloat16 t = __float2bfloat16(d * acc[j]);
        o[j] = *(ushort*)&t;
    }
}

// ================= k_front: scatter | pack mh | pack hll | dummy init =================

__global__ void __launch_bounds__(256) k_front(const int* __restrict__ src,
                       const int* __restrict__ dst, int* __restrict__ gcur,
                       uint* __restrict__ ebuf,
                       const int* __restrict__ mh, uint* __restrict__ mhp,
                       uint* __restrict__ mhA,
                       const int* __restrict__ hll, uint* __restrict__ hp,
                       uint* __restrict__ hllA) {
    __shared__ uint ecache[EDGES_PER_BLK];
    __shared__ int cnt[NBUCK];
    __shared__ int cur[NBUCK];
    int b = blockIdx.x;
    int t = threadIdx.x;
    if (b < SCAT_BLOCKS) {
        for (int i = t; i < NBUCK; i += 256) cnt[i] = 0;
        __syncthreads();
        int e0 = b * EDGES_PER_BLK;
        for (int i = t; i < EDGES_PER_BLK; i += 256) {
            int d = dst[e0 + i];
            int s = src[e0 + i];
            ecache[i] = ((uint)s << 16) | (uint)d;   // both < 65536
            atomicAdd(&cnt[d >> BSHIFT], 1);
        }
        __syncthreads();
        for (int bb = t; bb < NBUCK; bb += 256)
            cur[bb] = bb * CAPB + atomicAdd(&gcur[bb], cnt[bb]);
        __syncthreads();
        for (int i = t; i < EDGES_PER_BLK; i += 256) {
            uint en = ecache[i];
            uint d = en & 0xFFFFu;
            int p = atomicAdd(&cur[d >> BSHIFT], 1);
            ebuf[p] = ((en >> 16) << BSHIFT) | (d & (BNODES - 1));
        }
    } else if (b < SCAT_BLOCKS + MH2_BLOCKS * 2) {
        int i = (b - SCAT_BLOCKS) * 256 + t;
        int2 v = ((const int2*)mh)[i];
        uint u0 = __float_as_uint((float)v.x) >> 16;
        uint u1 = __float_as_uint((float)v.y) >> 16;
        mhp[i] = u0 | (u1 << 16);
    } else if (b < SCAT_BLOCKS + MH2_BLOCKS * 2 + HLL_BLOCKS) {
        int i = (b - SCAT_BLOCKS - MH2_BLOCKS * 2) * 256 + t;
        int4 v = ((const int4*)hll)[i];
        hp[i] = (uint)v.x | ((uint)v.y << 8) | ((uint)v.z << 16) | ((uint)v.w << 24);
    } else {
        if (t < 64) {
            mhp[(size_t)DUMMY * 64 + t] = 0xFFFFFFFFu;
            mhA[(size_t)DUMMY * 64 + t] = 0xFFFFFFFFu;
        } else if (t < 80) {
            hp[(size_t)DUMMY * 16 + (t - 64)] = 0u;
        } else if (t < 96) {
            hllA[(size_t)DUMMY * 16 + (t - 80)] = 0u;
        }
    }
}

// ================= k_fat1: csr | encoder =================

__global__ void __launch_bounds__(256) k_fat1(const uint* __restrict__ ebuf,
                      const int* __restrict__ gcur, int* __restrict__ pcur,
                      int2* __restrict__ off2, float* __restrict__ dis,
                      ushort* __restrict__ csr,
                      const float* __restrict__ x, const float* __restrict__ W_enc,
                      const float* __restrict__ b_enc, float* __restrict__ h) {
    __shared__ uint smem[SLICE_CAP + BNODES + 256 + 1];   // ~35.8 KB
    int b = blockIdx.x;
    int t = threadIdx.x;
    if (b < NBUCK) {
        uint* slice = smem;
        int* lcur = (int*)(smem + SLICE_CAP);
        int* ssum = (int*)(smem + SLICE_CAP + BNODES);
        int* sbase = (int*)(smem + SLICE_CAP + BNODES + 256);
        int lo = b << BSHIFT;
        int nbkt = min(BNODES, N_NODES - lo);
        int ebase = b * CAPB;
        int ecnt = gcur[b];
        lcur[t] = 0;
        __syncthreads();
        for (int i = t; i < ecnt; i += 256)
            atomicAdd(&lcur[ebuf[ebase + i] & (BNODES - 1)], 1);
        __syncthreads();
        int a0 = lcur[t];                      // in-degree (excl self)
        int plen = (t < nbkt) ? ((a0 + 8) & ~7) : 0;   // padded length incl self
        ssum[t] = plen;
        __syncthreads();
        for (int off = 1; off < 256; off <<= 1) {
            int u = (t >= off) ? ssum[t - off] : 0;
            __syncthreads();
            ssum[t] += u;
            __syncthreads();
        }
        int ppre = ssum[t] - plen;
        if (t == 255) sbase[0] = atomicAdd(pcur, ssum[255]);
        __syncthreads();
        int base = sbase[0];
        if (t < nbkt) {
            slice[ppre] = (uint)(lo + t);      // self-loop first
            lcur[t] = ppre + 1;
            off2[lo + t] = make_int2(base + ppre, base + ppre + plen);
            dis[lo + t] = rsqrtf((float)(a0 + 1));
        }
        __syncthreads();
        for (int i = t; i < ecnt; i += 256) {
            uint en = ebuf[ebase + i];
            int p = atomicAdd(&lcur[en & (BNODES - 1)], 1);
            slice[p] = en >> BSHIFT;
        }
        __syncthreads();
        if (t < nbkt)
            for (int i = lcur[t]; i < ppre + plen; ++i) slice[i] = DUMMY;
        __syncthreads();
        int total = ssum[255];
        for (int i = t; i < total; i += 256) csr[base + i] = (ushort)slice[i];
    } else {
        float* Ws = (float*)smem;
        for (int idx = t; idx < FDIM * HID; idx += 256) Ws[idx] = W_enc[idx];
        __syncthreads();
        int row = (b - NBUCK) * 64 + (t >> 2);
        int c0 = (t & 3) * 16;
        if (row >= N_NODES) return;
        float acc[16];
#pragma unroll
        for (int j = 0; j < 16; ++j) acc[j] = b_enc[c0 + j];
        const float4* xr = (const float4*)(x + (size_t)row * FDIM);
        for (int k4 = 0; k4 < FDIM / 4; ++k4) {
            float4 xv = xr[k4];
            const float* wr = Ws + (k4 * 4) * HID + c0;
#pragma unroll
            for (int j = 0; j < 16; ++j) acc[j] = fmaf(xv.x, wr[j], acc[j]);
#pragma unroll
            for (int j = 0; j < 16; ++j) acc[j] = fmaf(xv.y, wr[HID + j], acc[j]);
#pragma unroll
            for (int j = 0; j < 16; ++j) acc[j] = fmaf(xv.z, wr[2 * HID + j], acc[j]);
#pragma unroll
            for (int j = 0; j < 16; ++j) acc[j] = fmaf(xv.w, wr[3 * HID + j], acc[j]);
        }
        float* hr = h + (size_t)row * HID + c0;
#pragma unroll
        for (int j = 0; j < 16; ++j) hr[j] = acc[j];
    }
}

// ================= D1: mh0 | hll0 | conv0 =================

__global__ void __launch_bounds__(256) k_hopA(const int2* __restrict__ off2,
                    const ushort* __restrict__ csr,
                    const uint* __restrict__ mh_in, uint* __restrict__ mh_out_p,
                    const uint* __restrict__ hll_in, uint* __restrict__ hll_out_p,
                    float* __restrict__ cards,
                    const float* __restrict__ h, const float* __restrict__ W,
                    const float* __restrict__ dis, ushort* __restrict__ hWs) {
    __shared__ float Ws[HID * HID];
    int blk = blockIdx.x;
    int t = threadIdx.x;
    if (blk < MH2_BLOCKS) {
        int node = blk * 8 + (t >> 6) * 2 + ((t >> 5) & 1);
        mh_body(node, t & 31, off2, csr, mh_in, mh_out_p, nullptr);
    } else if (blk < MH2_BLOCKS + HLL_BLOCKS) {
        int node = (blk - MH2_BLOCKS) * 16 + (t >> 4);
        hll_body(node, t & 15, off2, csr, hll_in, hll_out_p, nullptr, cards, 0);
    } else {
        for (int i = t; i < HID * HID; i += 256) Ws[i] = W[i];
        __syncthreads();
        int row = (blk - MH2_BLOCKS - HLL_BLOCKS) * 64 + (t >> 2);
        int c0 = (t & 3) * 16;
        if (row > N_NODES) return;
        if (row == N_NODES) {           // dummy zero row
            ushort* o = hWs + (size_t)row * HID + c0;
#pragma unroll
            for (int j = 0; j < 16; ++j) o[j] = 0;
            return;
        }
        convmm_body(row, c0, h, Ws, dis, hWs);
    }
}

// ================= D2: mh1 | agg0 | hll1 =================

__global__ void __launch_bounds__(256) k_hopB(const int2* __restrict__ off2,
                    const ushort* __restrict__ csr,
                    const uint* __restrict__ mh_in, float* __restrict__ mh_out_f,
                    const uint* __restrict__ hWs32, const float* __restrict__ b0,
                    float* __restrict__ h_cur,
                    const uint* __restrict__ hll_in, float* __restrict__ hll_out_f,
                    float* __restrict__ cards, const float* __restrict__ dis) {
    int blk = blockIdx.x;
    int t = threadIdx.x;
    if (blk < MH2_BLOCKS) {
        int node = blk * 8 + (t >> 6) * 2 + ((t >> 5) & 1);
        mh_body(node, t & 31, off2, csr, mh_in, nullptr, mh_out_f);
    } else if (blk < MH2_BLOCKS + AGG2_BLOCKS) {
        int node = (blk - MH2_BLOCKS) * 8 + (t >> 6) * 2 + ((t >> 5) & 1);
        agg_body(node, t & 31, off2, csr, hWs32, dis, b0, h_cur, h_cur);
    } else {
        int node = (blk - MH2_BLOCKS - AGG2_BLOCKS) * 16 + (t >> 4);
        hll_body(node, t & 15, off2, csr, hll_in, nullptr, hll_out_f, cards, 1);
    }
}

// ================= D3: conv1 =================

__global__ void __launch_bounds__(256) k_conv(const float* __restrict__ h,
                         const float* __restrict__ W, const float* __restrict__ dis,
                         ushort* __restrict__ hWs) {
    __shared__ float Ws[HID * HID];
    for (int i = threadIdx.x; i < HID * HID; i += 256) Ws[i] = W[i];
    __syncthreads();
    int row = blockIdx.x * 64 + (threadIdx.x >> 2);
    int c0 = (threadIdx.x & 3) * 16;
    if (row > N_NODES) return;
    if (row == N_NODES) {
        ushort* o = hWs + (size_t)row * HID + c0;
#pragma unroll
        for (int j = 0; j < 16; ++j) o[j] = 0;
        return;
    }
    convmm_body(row, c0, h, Ws, dis, hWs);
}

// ================= D4: agg1 -> out_h =================

__global__ void __launch_bounds__(256) k_agg(const int2* __restrict__ off2,
                      const ushort* __restrict__ csr, const uint* __restrict__ hWs32,
                      const float* __restrict__ dis, const float* __restrict__ b,
                      const float* __restrict__ h_in, float* __restrict__ h_out) {
    int t = threadIdx.x;
    int node = blockIdx.x * 8 + (t >> 6) * 2 + ((t >> 5) & 1);
    agg_body(node, t & 31, off2, csr, hWs32, dis, b, h_in, h_out);
}

// ---------------- driver ----------------

static inline char* align256(char* p) {
    return (char*)(((uintptr_t)p + 255) & ~(uintptr_t)255);
}

extern "C" void kernel_launch(void* const* d_in, const int* in_sizes, int n_in,
                              void* d_out, int out_size, void* d_ws, size_t ws_size,
                              hipStream_t stream) {
    const float* x       = (const float*)d_in[0];
    const int*   ei      = (const int*)d_in[1];
    const int*   mh0     = (const int*)d_in[2];
    const int*   hll0    = (const int*)d_in[3];
    const float* W_enc   = (const float*)d_in[4];
    const float* b_enc   = (const float*)d_in[5];
    const float* W_convs = (const float*)d_in[6];
    const float* b_convs = (const float*)d_in[7];

    float* out       = (float*)d_out;
    float* out_h     = out;
    float* out_cards = out + (size_t)N_NODES * HID;
    float* out_mh    = out_cards + (size_t)N_NODES * 2;
    float* out_hll   = out_mh + (size_t)N_NODES * NPERM;

    char* w = (char*)d_ws;
    int*   gcur    = (int*)w;   w += (size_t)NBUCK * 4;
    int*   pcur    = (int*)w;   w = align256(w + 4);
    int2*  off2    = (int2*)w;  w = align256(w + (size_t)N_NODES * 8);
    float* dis     = (float*)w; w = align256(w + (size_t)N_NODES * 4);
    ushort* csr    = (ushort*)w; w = align256(w + (size_t)(N_EDGES + 8 * N_NODES) * 2);
    uint*  mhp0    = (uint*)w;  w = align256(w + (size_t)(N_NODES + 1) * 64 * 4);
    uint*  mhA     = (uint*)w;  w = align256(w + (size_t)(N_NODES + 1) * 64 * 4);
    uint*  hp0     = (uint*)w;  w = align256(w + (size_t)(N_NODES + 1) * 16 * 4);
    uint*  hllA    = (uint*)w;  w = align256(w + (size_t)(N_NODES + 1) * 16 * 4);
    float* h_cur   = (float*)w; w = align256(w + (size_t)N_NODES * HID * 4);
    ushort* hWs    = (ushort*)w; w = align256(w + (size_t)(N_NODES + 1) * HID * 2);
    uint*  ebuf    = mhA;  // build-phase alias (196*6144 uints = 4.8MB < 12.8MB extent);
                           // dummy row at 12.8MB offset untouched by ebuf

    const int* src = ei;
    const int* dst = ei + N_EDGES;

    // zero gcur (+pcur, adjacent) -> fixed bucket bases added in-kernel
    hipMemsetAsync(gcur, 0, (size_t)(NBUCK + 1) * 4, stream);
    // F1: scatter | pack mh | pack hll | dummy init
    k_front<<<SCAT_BLOCKS + MH2_BLOCKS * 2 + HLL_BLOCKS + 1, 256, 0, stream>>>(
        src, dst, gcur, ebuf, mh0, mhp0, mhA, hll0, hp0, hllA);
    // F2: csr | encoder
    k_fat1<<<NBUCK + CONV_BLOCKS, 256, 0, stream>>>(
        ebuf, gcur, pcur, off2, dis, csr, x, W_enc, b_enc, h_cur);

    // D1: mh0 | hll0 | conv0
    k_hopA<<<MH2_BLOCKS + HLL_BLOCKS + CONV_BLOCKS + 1, 256, 0, stream>>>(
        off2, csr, mhp0, mhA, hp0, hllA, out_cards, h_cur, W_convs, dis, hWs);
    // D2: mh1 | agg0 | hll1
    k_hopB<<<MH2_BLOCKS + AGG2_BLOCKS + HLL_BLOCKS, 256, 0, stream>>>(
        off2, csr, mhA, out_mh, (const uint*)hWs, b_convs, h_cur, hllA, out_hll, out_cards, dis);
    // D3: conv1
    k_conv<<<CONV_BLOCKS + 1, 256, 0, stream>>>(h_cur, W_convs + HID * HID, dis, hWs);
    // D4: agg1 -> out_h
    k_agg<<<AGG2_BLOCKS, 256, 0, stream>>>(off2, csr, (const uint*)hWs, dis, b_convs + HID, h_cur, out_h);
}